// Round 7
// baseline (181.977 us; speedup 1.0000x reference)
//
#include <hip/hip_runtime.h>
#include <math.h>

#define S_LEN 1024
#define BATCH 2
#define DM 512
#define DI 1024
#define DS 128
#define DTR 32
#define CL 64            // chunk length
#define NC (S_LEN / CL)  // 16 chunks

typedef unsigned short ushortT;
typedef __attribute__((ext_vector_type(8))) short short8;
typedef __attribute__((ext_vector_type(4))) float f32x4;

__device__ __forceinline__ ushortT f2b(float f) {
  unsigned u = __builtin_bit_cast(unsigned, f);
  unsigned r = (u + 0x7fff + ((u >> 16) & 1)) >> 16;  // RNE
  return (ushortT)r;
}
__device__ __forceinline__ float b2f(ushortT h) {
  return __builtin_bit_cast(float, (unsigned)h << 16);
}

#define GLOAD16(g, l)                                                     \
  __builtin_amdgcn_global_load_lds(                                       \
      (const __attribute__((address_space(1))) void*)(g),                 \
      (__attribute__((address_space(3))) void*)(l), 16, 0, 0)

// ---- bf16 MFMA GEMM: C[M,N] = A[M,K] @ Bt[Npad,K]^T -------------------------
// 128x128 tile, 256 threads = 4 waves (2x2). Flat grid + XCD swizzle
// (gridDim.x % 8 == 0 for all call sites). MODE 0: fp32 out; 1: bf16 out.
template<int MODE>
__global__ __launch_bounds__(256) void gemm_mfma(
    const ushortT* __restrict__ A, const ushortT* __restrict__ Bt,
    void* __restrict__ Cout, int N, int K, int ldc, int nbx) {
  __shared__ ushortT As[128 * 32];
  __shared__ ushortT Bs[128 * 32];
  const int nwg = gridDim.x;
  const int bid = blockIdx.x;
  const int flat = (bid & 7) * (nwg >> 3) + (bid >> 3);  // XCD-contiguous
  const int bxi = flat % nbx, byi = flat / nbx;
  const int bm = byi * 128, bn = bxi * 128;
  const int tid = threadIdx.x;
  const int l = tid & 63, w = tid >> 6;
  const int wr = w >> 1, wc = w & 1;
  const int srow = l >> 2, scol = (l & 3) * 8;
  f32x4 acc[4][4] = {};
  for (int k0 = 0; k0 < K; k0 += 32) {
#pragma unroll
    for (int j = 0; j < 2; ++j) {
      int sub = w * 2 + j;
      const ushortT* gA = A + (size_t)(bm + sub * 16 + srow) * K + k0 + scol;
      GLOAD16(gA, &As[sub * 512]);
      const ushortT* gB = Bt + (size_t)(bn + sub * 16 + srow) * K + k0 + scol;
      GLOAD16(gB, &Bs[sub * 512]);
    }
    __syncthreads();
    short8 a[4], b[4];
#pragma unroll
    for (int m = 0; m < 4; ++m)
      a[m] = *(const short8*)&As[(wr * 64 + m * 16 + (l & 15)) * 32 + (l >> 4) * 8];
#pragma unroll
    for (int n = 0; n < 4; ++n)
      b[n] = *(const short8*)&Bs[(wc * 64 + n * 16 + (l & 15)) * 32 + (l >> 4) * 8];
#pragma unroll
    for (int m = 0; m < 4; ++m)
#pragma unroll
      for (int n = 0; n < 4; ++n)
        acc[m][n] = __builtin_amdgcn_mfma_f32_16x16x32_bf16(a[m], b[n], acc[m][n], 0, 0, 0);
    __syncthreads();
  }
#pragma unroll
  for (int m = 0; m < 4; ++m) {
    int grow = bm + wr * 64 + m * 16 + (l >> 4) * 4;
#pragma unroll
    for (int n = 0; n < 4; ++n) {
      int gcol = bn + wc * 64 + n * 16 + (l & 15);
      if (gcol >= N) continue;
#pragma unroll
      for (int i = 0; i < 4; ++i) {
        float v = acc[m][n][i];
        if (MODE == 1)
          ((ushortT*)Cout)[(size_t)(grow + i) * ldc + gcol] = f2b(v);
        else
          ((float*)Cout)[(size_t)(grow + i) * ldc + gcol] = v;
      }
    }
  }
}

// ---- prep_all: 3 weight transposes (fp32->bf16, [K,N]->[Npad,K]) + x cvt ----
// blocks [0,1024) W_in; [1024,1408) W_x(pad 384); [1408,1920) W_out;
// [1920,2944) x -> x_bf.
__global__ __launch_bounds__(256) void prep_all(
    const float* __restrict__ W_in, const float* __restrict__ W_x,
    const float* __restrict__ W_out, const float* __restrict__ x,
    ushortT* __restrict__ Wt_in, ushortT* __restrict__ Wt_x,
    ushortT* __restrict__ Wt_out, ushortT* __restrict__ x_bf) {
  __shared__ float tb[32][33];
  int bid = blockIdx.x;
  int tx = threadIdx.x, ty = threadIdx.y;  // (32,8)
  const float* in; ushortT* out; int K, N, bx, by;
  if (bid < 1024)      { in = W_in;  out = Wt_in;  K = 512;  N = 2048; bx = bid & 63; by = bid >> 6; }
  else if (bid < 1408) { int t2 = bid - 1024; in = W_x;   out = Wt_x;   K = 1024; N = 288; bx = t2 % 12; by = t2 / 12; }
  else if (bid < 1920) { int t2 = bid - 1408; in = W_out; out = Wt_out; K = 1024; N = 512; bx = t2 % 16; by = t2 / 16; }
  else {
    int i = (bid - 1920) * 256 + ty * 32 + tx;
    float4 v = ((const float4*)x)[i];
    ushort4 o; o.x = f2b(v.x); o.y = f2b(v.y); o.z = f2b(v.z); o.w = f2b(v.w);
    ((ushort4*)x_bf)[i] = o;
    return;
  }
  int n0 = bx * 32, k0 = by * 32;
  if (n0 < N) {
#pragma unroll
    for (int i = 0; i < 4; ++i)
      tb[ty + 8 * i][tx] = in[(size_t)(k0 + ty + 8 * i) * N + n0 + tx];
    __syncthreads();
#pragma unroll
    for (int i = 0; i < 4; ++i)
      out[(size_t)(n0 + ty + 8 * i) * K + k0 + tx] = f2b(tb[tx][ty + 8 * i]);
  } else {
#pragma unroll
    for (int i = 0; i < 4; ++i)
      out[(size_t)(n0 + ty + 8 * i) * K + k0 + tx] = 0;
  }
}

// ---- depthwise causal conv, 4 d per thread (ushort4) ------------------------
__global__ __launch_bounds__(256) void conv_kernel(
    const ushortT* __restrict__ xr, const float* __restrict__ w,
    const float* __restrict__ b, ushortT* __restrict__ u) {
  int idx = blockIdx.x * blockDim.x + threadIdx.x;  // over B*S*DI/4 = 524288
  int g = idx & 255;                 // d-group (d = 4g)
  int s = (idx >> 8) & (S_LEN - 1);
  int bb = idx >> 18;
  int d = g * 4;
  float4 bias = *(const float4*)&b[d];
  float4 w0 = *(const float4*)&w[(d + 0) * 4];
  float4 w1 = *(const float4*)&w[(d + 1) * 4];
  float4 w2 = *(const float4*)&w[(d + 2) * 4];
  float4 w3 = *(const float4*)&w[(d + 3) * 4];
  float a0 = bias.x, a1 = bias.y, a2 = bias.z, a3 = bias.w;
  const ushortT* xs = xr + (size_t)(bb * S_LEN) * (2 * DI) + d;
#pragma unroll
  for (int k = 0; k < 4; ++k) {
    int si = s - 3 + k;
    if (si >= 0) {
      ushort4 v = *(const ushort4*)&xs[(size_t)si * (2 * DI)];
      float wk0 = ((const float*)&w0)[k], wk1 = ((const float*)&w1)[k];
      float wk2 = ((const float*)&w2)[k], wk3 = ((const float*)&w3)[k];
      a0 = fmaf(b2f(v.x), wk0, a0);
      a1 = fmaf(b2f(v.y), wk1, a1);
      a2 = fmaf(b2f(v.z), wk2, a2);
      a3 = fmaf(b2f(v.w), wk3, a3);
    }
  }
  ushort4 o; o.x = f2b(a0); o.y = f2b(a1); o.z = f2b(a2); o.w = f2b(a3);
  *(ushort4*)&u[(size_t)idx * 4] = o;
}

// ---- prep_bc: per chunk bc: dbl -> Cb (global), btr (B^T), G=tril(C.B^T) ----
__global__ __launch_bounds__(256) void prep_bc(
    const float* __restrict__ dbl, ushortT* __restrict__ Cb,
    ushortT* __restrict__ btr, ushortT* __restrict__ G) {
  __shared__ ushortT Bl[64][132];  // padded stride vs bank conflicts
  __shared__ ushortT Cl[64][132];
  const int bc = blockIdx.x, t = threadIdx.x;
  // load 64 rows x 256 cols (B|C) fp32, cvt to bf16 in LDS
  for (int i = 0; i < 64; ++i) {
    int idx = i * 256 + t;
    int row = idx >> 8, col = idx & 255;
    float v = dbl[(size_t)(bc * 64 + row) * 288 + 32 + col];
    if (col < 128) Bl[row][col] = f2b(v);
    else Cl[row][col - 128] = f2b(v);
  }
  __syncthreads();
  // Cb global (rows bc*64..): ushort4 coalesced
  for (int i = 0; i < 8; ++i) {
    int idx4 = i * 256 + t;            // 2048 ushort4 = 8192 elems
    int row = idx4 >> 5, c4 = (idx4 & 31) * 4;
    ushort4 o;
    o.x = Cl[row][c4]; o.y = Cl[row][c4 + 1];
    o.z = Cl[row][c4 + 2]; o.w = Cl[row][c4 + 3];
    *(ushort4*)&Cb[(size_t)(bc * 64 + row) * 128 + c4] = o;
  }
  // btr[bc][n][s] = B[s][n]
  for (int i = 0; i < 32; ++i) {
    int idx = i * 256 + t;             // 8192
    int n = idx >> 6, s = idx & 63;
    btr[(size_t)bc * 8192 + idx] = Bl[s][n];
  }
  // G = tril(C @ B^T) via MFMA from LDS
  const int l = t & 63, w = t >> 6;
  f32x4 acc[4] = {};
#pragma unroll
  for (int kk = 0; kk < 4; ++kk) {
    short8 a = *(const short8*)&Cl[w * 16 + (l & 15)][kk * 32 + (l >> 4) * 8];
#pragma unroll
    for (int nf = 0; nf < 4; ++nf) {
      short8 bb = *(const short8*)&Bl[nf * 16 + (l & 15)][kk * 32 + (l >> 4) * 8];
      acc[nf] = __builtin_amdgcn_mfma_f32_16x16x32_bf16(a, bb, acc[nf], 0, 0, 0);
    }
  }
#pragma unroll
  for (int nf = 0; nf < 4; ++nf) {
    int s = nf * 16 + (l & 15);
#pragma unroll
    for (int i = 0; i < 4; ++i) {
      int tr = w * 16 + (l >> 4) * 4 + i;
      float v = (s <= tr) ? acc[nf][i] : 0.f;
      G[((size_t)bc * 64 + tr) * 64 + s] = f2b(v);
    }
  }
}

// ---- dtdecay: dt-proj (fp32) + softplus/clip + cumprod + ut transpose -------
// grid (8 d-tiles, 32 bc), 128 threads; thread owns d = dg*128 + tid.
__global__ __launch_bounds__(128) void dtdecay(
    const float* __restrict__ dbl, const float* __restrict__ W_dt,
    const float* __restrict__ b_dt, const ushortT* __restrict__ u_bf,
    float* __restrict__ D, ushortT* __restrict__ ut) {
  __shared__ float Wl[32][128];
  __shared__ float dtl[64][32];
  __shared__ ushortT lt[128 * 66];
  const int tid = threadIdx.x;
  const int dg = blockIdx.x, bc = blockIdx.y;
  const int b = bc >> 4, c = bc & 15;
  const int d = dg * 128 + tid;
#pragma unroll 8
  for (int k = 0; k < 32; ++k) Wl[k][tid] = W_dt[(size_t)k * DI + d];
  for (int i = 0; i < 16; ++i) {
    int idx = i * 128 + tid;
    int row = idx >> 5, col = idx & 31;
    dtl[row][col] = dbl[(size_t)(bc * 64 + row) * 288 + col];
  }
  __syncthreads();
  float bias = b_dt[d] + 1e-4f;
  float cum = 1.f;
  size_t rb = ((size_t)(b * S_LEN + c * CL)) * DI + d;
  for (int s = 0; s < CL; ++s) {
    float acc = bias;
#pragma unroll
    for (int k = 0; k < 32; ++k) acc = fmaf(dtl[s][k], Wl[k][tid], acc);
    acc = (acc > 20.f) ? acc : log1pf(expf(acc));
    acc = fminf(fmaxf(acc, 0.001f), 0.1f);
    cum *= (1.f - acc);
    D[rb + (size_t)s * DI] = cum;
    float uu = b2f(u_bf[rb + (size_t)s * DI]);
    lt[tid * 66 + s] = f2b(uu / cum);
  }
  __syncthreads();
#pragma unroll
  for (int it = 0; it < 16; ++it) {
    int r = it * 8 + (tid >> 4);
    int s4 = (tid & 15) * 4;
    ushort4 o;
    o.x = lt[r * 66 + s4];
    o.y = lt[r * 66 + s4 + 1];
    o.z = lt[r * 66 + s4 + 2];
    o.w = lt[r * 66 + s4 + 3];
    *(ushort4*)&ut[(((size_t)bc * DI) + dg * 128 + r) * CL + s4] = o;
  }
}

// ---- Z[bc][d][n] = sum_s ut[d,s] * Btr[n,s]  (bf16 out into zb layout) ------
__global__ __launch_bounds__(256) void gemm_z(
    const ushortT* __restrict__ ut, const ushortT* __restrict__ btr,
    ushortT* __restrict__ zb) {
  __shared__ ushortT As[128 * 32];
  __shared__ ushortT Bs[128 * 32];
  const int tid = threadIdx.x;
  const int l = tid & 63, w = tid >> 6;
  const int wr = w >> 1, wc = w & 1;
  const int bc = blockIdx.z;
  const int b = bc >> 4, c = bc & 15;
  const int bm = blockIdx.y * 128;
  const ushortT* A = ut + (size_t)bc * DI * CL;
  const ushortT* Bt = btr + (size_t)bc * DS * CL;
  const int srow = l >> 2, scol = (l & 3) * 8;
  f32x4 acc[4][4] = {};
  for (int k0 = 0; k0 < CL; k0 += 32) {
#pragma unroll
    for (int j = 0; j < 2; ++j) {
      int sub = w * 2 + j;
      GLOAD16(A + (size_t)(bm + sub * 16 + srow) * CL + k0 + scol, &As[sub * 512]);
      GLOAD16(Bt + (size_t)(sub * 16 + srow) * CL + k0 + scol, &Bs[sub * 512]);
    }
    __syncthreads();
    short8 a[4], bb[4];
#pragma unroll
    for (int m = 0; m < 4; ++m)
      a[m] = *(const short8*)&As[(wr * 64 + m * 16 + (l & 15)) * 32 + (l >> 4) * 8];
#pragma unroll
    for (int n = 0; n < 4; ++n)
      bb[n] = *(const short8*)&Bs[(wc * 64 + n * 16 + (l & 15)) * 32 + (l >> 4) * 8];
#pragma unroll
    for (int m = 0; m < 4; ++m)
#pragma unroll
      for (int n = 0; n < 4; ++n)
        acc[m][n] = __builtin_amdgcn_mfma_f32_16x16x32_bf16(a[m], bb[n], acc[m][n], 0, 0, 0);
    __syncthreads();
  }
#pragma unroll
  for (int m = 0; m < 4; ++m) {
    int d = bm + wr * 64 + m * 16 + (l >> 4) * 4;
#pragma unroll
    for (int n = 0; n < 4; ++n) {
      int gn = wc * 64 + n * 16 + (l & 15);
#pragma unroll
      for (int i = 0; i < 4; ++i)
        zb[(((size_t)(b * DI + d + i)) * NC + c) * 128 + gn] = f2b(acc[m][n][i]);
    }
  }
}

// ---- pass2: h_entry chain over chunks; hstb bf16 = entry state --------------
__global__ __launch_bounds__(256) void scan_pass2(
    const ushortT* __restrict__ zb, const float* __restrict__ D,
    ushortT* __restrict__ hstb) {
  int wid = (blockIdx.x * blockDim.x + threadIdx.x) >> 6;  // 0..2047 = b*DI+d
  int lane = threadIdx.x & 63;
  int b = wid >> 10, d = wid & (DI - 1);
  size_t base = (size_t)wid * NC * 128;
  float h0 = 0.f, h1 = 0.f;
  for (int c = 0; c < NC; ++c) {
    float dend = D[((size_t)(b * S_LEN + c * CL + CL - 1)) * DI + d];
    ushort2 z2 = *(const ushort2*)&zb[base + c * 128 + 2 * lane];
    ushort2 he;
    he.x = f2b(h0); he.y = f2b(h1);
    *(ushort2*)&hstb[base + c * 128 + 2 * lane] = he;
    h0 = dend * (h0 + b2f(z2.x));
    h1 = dend * (h1 + b2f(z2.y));
  }
}

// ---- Y: yr[t,d] = bf16( D[t,d]*( G@ut + Cb@hstb ) + res ) -------------------
__global__ __launch_bounds__(256) void gemm_y(
    const ushortT* __restrict__ G, const ushortT* __restrict__ ut,
    const ushortT* __restrict__ Cb, const ushortT* __restrict__ hstb,
    const float* __restrict__ D, const ushortT* __restrict__ xr_bf,
    ushortT* __restrict__ yr) {
  const int tid = threadIdx.x;
  const int l = tid & 63, w = tid >> 6;
  const int bc = blockIdx.y, d0 = blockIdx.x * 256;
  const int b = bc >> 4, c = bc & 15;
  const int brow = b * S_LEN + c * CL;
  f32x4 acc[4][4] = {};
  // phase 1: K=64 (s): A = G rows, Bt = ut rows
#pragma unroll
  for (int kk = 0; kk < 2; ++kk) {
    short8 a[4], bb[4];
#pragma unroll
    for (int m = 0; m < 4; ++m)
      a[m] = *(const short8*)&G[((size_t)bc * 64 + m * 16 + (l & 15)) * 64 + kk * 32 + (l >> 4) * 8];
#pragma unroll
    for (int n = 0; n < 4; ++n) {
      int d = d0 + w * 64 + n * 16 + (l & 15);
      bb[n] = *(const short8*)&ut[((size_t)bc * DI + d) * CL + kk * 32 + (l >> 4) * 8];
    }
#pragma unroll
    for (int m = 0; m < 4; ++m)
#pragma unroll
      for (int n = 0; n < 4; ++n)
        acc[m][n] = __builtin_amdgcn_mfma_f32_16x16x32_bf16(a[m], bb[n], acc[m][n], 0, 0, 0);
  }
  // phase 2: K=128 (n): A = Cb rows, Bt = hstb rows
#pragma unroll
  for (int kk = 0; kk < 4; ++kk) {
    short8 a[4], bb[4];
#pragma unroll
    for (int m = 0; m < 4; ++m)
      a[m] = *(const short8*)&Cb[((size_t)brow + m * 16 + (l & 15)) * 128 + kk * 32 + (l >> 4) * 8];
#pragma unroll
    for (int n = 0; n < 4; ++n) {
      int d = d0 + w * 64 + n * 16 + (l & 15);
      bb[n] = *(const short8*)&hstb[((size_t)(b * DI + d)) * (NC * 128) + c * 128 + kk * 32 + (l >> 4) * 8];
    }
#pragma unroll
    for (int m = 0; m < 4; ++m)
#pragma unroll
      for (int n = 0; n < 4; ++n)
        acc[m][n] = __builtin_amdgcn_mfma_f32_16x16x32_bf16(a[m], bb[n], acc[m][n], 0, 0, 0);
  }
#pragma unroll
  for (int m = 0; m < 4; ++m) {
#pragma unroll
    for (int n = 0; n < 4; ++n) {
      int d = d0 + w * 64 + n * 16 + (l & 15);
#pragma unroll
      for (int i = 0; i < 4; ++i) {
        int gr = brow + m * 16 + (l >> 4) * 4 + i;
        float Dv = D[(size_t)gr * DI + d];
        float res = b2f(xr_bf[(size_t)gr * 2048 + 1024 + d]);
        yr[(size_t)gr * DI + d] = f2b(acc[m][n][i] * Dv + res);
      }
    }
  }
}

extern "C" void kernel_launch(void* const* d_in, const int* in_sizes, int n_in,
                              void* d_out, int out_size, void* d_ws, size_t ws_size,
                              hipStream_t stream) {
  const float* x      = (const float*)d_in[0];
  const float* W_in   = (const float*)d_in[1];
  const float* conv_w = (const float*)d_in[2];
  const float* conv_b = (const float*)d_in[3];
  const float* W_x    = (const float*)d_in[4];
  const float* W_dt   = (const float*)d_in[5];
  const float* b_dt   = (const float*)d_in[6];
  const float* W_out  = (const float*)d_in[7];
  float* out = (float*)d_out;
  float* ws = (float*)d_ws;

  // workspace (float units), all disjoint; total 13,959,168 floats = 55.8 MB
  ushortT* xr_bf = (ushortT*)ws;                  // [2048,2048] bf16
  ushortT* u_bf  = (ushortT*)(ws + 2097152);      // [2048,1024] bf16
  float*   dbl   = ws + 3145728;                  // [2048,288] fp32
  float*   Dc    = ws + 3735552;                  // [2048,1024] fp32
  ushortT* ut    = (ushortT*)(ws + 5832704);      // [32,1024,64] bf16
  ushortT* zb    = (ushortT*)(ws + 6881280);      // [2048,16,128] bf16
  ushortT* hstb  = (ushortT*)(ws + 8978432);      // [2048,16,128] bf16
  ushortT* Cb    = (ushortT*)(ws + 11075584);     // [2048,128] bf16
  ushortT* btr   = (ushortT*)(ws + 11206656);     // [32,128,64] bf16
  ushortT* G     = (ushortT*)(ws + 11337728);     // [32,64,64] bf16
  ushortT* x_bf  = (ushortT*)(ws + 11403264);     // [2048,512] bf16
  ushortT* Wt_in = (ushortT*)(ws + 11927552);     // [2048,512] bf16
  ushortT* Wt_x  = (ushortT*)(ws + 12451840);     // [384,1024] bf16
  ushortT* Wt_out= (ushortT*)(ws + 12648448);     // [512,1024] bf16
  ushortT* yr_bf = (ushortT*)(ws + 12910592);     // [2048,1024] bf16

  dim3 blk(256);
  // 1) all weight transposes + x cvt
  prep_all<<<2944, dim3(32, 8), 0, stream>>>(W_in, W_x, W_out, x, Wt_in, Wt_x, Wt_out, x_bf);
  // 2) in-proj: xr = x @ W_in (bf16)  M=2048 N=2048 K=512; grid 16x16 flat
  gemm_mfma<1><<<256, blk, 0, stream>>>(x_bf, Wt_in, xr_bf, 2 * DI, DM, 2 * DI, 16);
  // 3) conv -> u (bf16)
  conv_kernel<<<2048, blk, 0, stream>>>(xr_bf, conv_w, conv_b, u_bf);
  // 4) x-proj: dbl = u @ W_x (fp32)   M=2048 N=288 K=1024; grid 3x16 flat
  gemm_mfma<0><<<48, blk, 0, stream>>>(u_bf, Wt_x, dbl, DTR + 2 * DS, DI, DTR + 2 * DS, 3);
  // 5) per-chunk prep: Cb, btr, G
  prep_bc<<<32, blk, 0, stream>>>(dbl, Cb, btr, G);
  // 6) dt-proj + decay + ut
  dtdecay<<<dim3(8, 32), dim3(128), 0, stream>>>(dbl, W_dt, b_dt, u_bf, Dc, ut);
  // 7) Z = ut @ Btr^T per chunk -> zb
  gemm_z<<<dim3(1, 8, 32), blk, 0, stream>>>(ut, btr, zb);
  // 8) chunk-boundary combine -> hstb (entry states, bf16)
  scan_pass2<<<512, blk, 0, stream>>>(zb, Dc, hstb);
  // 9) Y = D*(G@ut + C@h_entry) + res -> yr_bf
  gemm_y<<<dim3(4, 32), blk, 0, stream>>>(G, ut, Cb, hstb, Dc, xr_bf, yr_bf);
  // 10) out-proj: out = yr @ W_out (fp32)  M=2048 N=512 K=1024; grid 4x16 flat
  gemm_mfma<0><<<64, blk, 0, stream>>>(yr_bf, Wt_out, out, DM, DI, DM, 4);
}

// Round 8
// 174.295 us; speedup vs baseline: 1.0441x; 1.0441x over previous
//
#include <hip/hip_runtime.h>
#include <math.h>

#define S_LEN 1024
#define BATCH 2
#define DM 512
#define DI 1024
#define DS 128
#define DTR 32
#define CL 64            // chunk length
#define NC (S_LEN / CL)  // 16 chunks

typedef unsigned short ushortT;
typedef __attribute__((ext_vector_type(8))) short short8;
typedef __attribute__((ext_vector_type(4))) float f32x4;

__device__ __forceinline__ ushortT f2b(float f) {
  unsigned u = __builtin_bit_cast(unsigned, f);
  unsigned r = (u + 0x7fff + ((u >> 16) & 1)) >> 16;  // RNE
  return (ushortT)r;
}
__device__ __forceinline__ float b2f(ushortT h) {
  return __builtin_bit_cast(float, (unsigned)h << 16);
}

#define GLOAD16(g, l)                                                     \
  __builtin_amdgcn_global_load_lds(                                       \
      (const __attribute__((address_space(1))) void*)(g),                 \
      (__attribute__((address_space(3))) void*)(l), 16, 0, 0)

// ---- bf16 MFMA GEMM: C[M,N] = A[M,K] @ Bt[Npad,K]^T -------------------------
// 128x128 tile, 256 threads = 4 waves (2x2). Flat grid + XCD swizzle
// (gridDim.x % 8 == 0 at all call sites). MODE 0: fp32 out; 1: bf16 out;
// 3: om = 1 - clip(softplus(v + bias + 1e-4)) fp32 out (dt-proj epilogue).
template<int MODE>
__global__ __launch_bounds__(256) void gemm_mfma(
    const ushortT* __restrict__ A, const ushortT* __restrict__ Bt,
    const float* __restrict__ bias,
    void* __restrict__ Cout, int N, int K, int ldc, int nbx) {
  __shared__ ushortT As[128 * 32];
  __shared__ ushortT Bs[128 * 32];
  const int nwg = gridDim.x;
  const int bid = blockIdx.x;
  const int flat = (bid & 7) * (nwg >> 3) + (bid >> 3);  // XCD-contiguous
  const int bxi = flat % nbx, byi = flat / nbx;
  const int bm = byi * 128, bn = bxi * 128;
  const int tid = threadIdx.x;
  const int l = tid & 63, w = tid >> 6;
  const int wr = w >> 1, wc = w & 1;
  const int srow = l >> 2, scol = (l & 3) * 8;
  f32x4 acc[4][4] = {};
  for (int k0 = 0; k0 < K; k0 += 32) {
#pragma unroll
    for (int j = 0; j < 2; ++j) {
      int sub = w * 2 + j;
      const ushortT* gA = A + (size_t)(bm + sub * 16 + srow) * K + k0 + scol;
      GLOAD16(gA, &As[sub * 512]);
      const ushortT* gB = Bt + (size_t)(bn + sub * 16 + srow) * K + k0 + scol;
      GLOAD16(gB, &Bs[sub * 512]);
    }
    __syncthreads();
    short8 a[4], b[4];
#pragma unroll
    for (int m = 0; m < 4; ++m)
      a[m] = *(const short8*)&As[(wr * 64 + m * 16 + (l & 15)) * 32 + (l >> 4) * 8];
#pragma unroll
    for (int n = 0; n < 4; ++n)
      b[n] = *(const short8*)&Bs[(wc * 64 + n * 16 + (l & 15)) * 32 + (l >> 4) * 8];
#pragma unroll
    for (int m = 0; m < 4; ++m)
#pragma unroll
      for (int n = 0; n < 4; ++n)
        acc[m][n] = __builtin_amdgcn_mfma_f32_16x16x32_bf16(a[m], b[n], acc[m][n], 0, 0, 0);
    __syncthreads();
  }
#pragma unroll
  for (int m = 0; m < 4; ++m) {
    int grow = bm + wr * 64 + m * 16 + (l >> 4) * 4;
#pragma unroll
    for (int n = 0; n < 4; ++n) {
      int gcol = bn + wc * 64 + n * 16 + (l & 15);
      if (gcol >= N) continue;
#pragma unroll
      for (int i = 0; i < 4; ++i) {
        float v = acc[m][n][i];
        if (MODE == 1)
          ((ushortT*)Cout)[(size_t)(grow + i) * ldc + gcol] = f2b(v);
        else if (MODE == 3) {
          v += bias[gcol] + 1e-4f;
          v = (v > 20.f) ? v : log1pf(expf(v));
          v = fminf(fmaxf(v, 0.001f), 0.1f);
          ((float*)Cout)[(size_t)(grow + i) * ldc + gcol] = 1.f - v;
        } else
          ((float*)Cout)[(size_t)(grow + i) * ldc + gcol] = v;
      }
    }
  }
}

// ---- prep_all: weight transposes (fp32->bf16, [K,N]->[Npad,K]) + x cvt ------
// blocks [0,1024) W_in; [1024,1408) W_x(pad 384); [1408,1920) W_out;
// [1920,1952) W_dt; [1952,2976) x -> x_bf.
__global__ __launch_bounds__(256) void prep_all(
    const float* __restrict__ W_in, const float* __restrict__ W_x,
    const float* __restrict__ W_out, const float* __restrict__ W_dt,
    const float* __restrict__ x,
    ushortT* __restrict__ Wt_in, ushortT* __restrict__ Wt_x,
    ushortT* __restrict__ Wt_out, ushortT* __restrict__ Wt_dt,
    ushortT* __restrict__ x_bf) {
  __shared__ float tb[32][33];
  int bid = blockIdx.x;
  int tx = threadIdx.x, ty = threadIdx.y;  // (32,8)
  const float* in; ushortT* out; int K, N, bx, by;
  if (bid < 1024)      { in = W_in;  out = Wt_in;  K = 512;  N = 2048; bx = bid & 63; by = bid >> 6; }
  else if (bid < 1408) { int t2 = bid - 1024; in = W_x;   out = Wt_x;   K = 1024; N = 288;  bx = t2 % 12; by = t2 / 12; }
  else if (bid < 1920) { int t2 = bid - 1408; in = W_out; out = Wt_out; K = 1024; N = 512;  bx = t2 % 16; by = t2 / 16; }
  else if (bid < 1952) { int t2 = bid - 1920; in = W_dt;  out = Wt_dt;  K = 32;   N = 1024; bx = t2;      by = 0; }
  else {
    int i = (bid - 1952) * 256 + ty * 32 + tx;
    float4 v = ((const float4*)x)[i];
    ushort4 o; o.x = f2b(v.x); o.y = f2b(v.y); o.z = f2b(v.z); o.w = f2b(v.w);
    ((ushort4*)x_bf)[i] = o;
    return;
  }
  int n0 = bx * 32, k0 = by * 32;
  if (n0 < N) {
#pragma unroll
    for (int i = 0; i < 4; ++i)
      tb[ty + 8 * i][tx] = in[(size_t)(k0 + ty + 8 * i) * N + n0 + tx];
    __syncthreads();
#pragma unroll
    for (int i = 0; i < 4; ++i)
      out[(size_t)(n0 + ty + 8 * i) * K + k0 + tx] = f2b(tb[tx][ty + 8 * i]);
  } else {
#pragma unroll
    for (int i = 0; i < 4; ++i)
      out[(size_t)(n0 + ty + 8 * i) * K + k0 + tx] = 0;
  }
}

// ---- depthwise causal conv, 4 d per thread (ushort4) ------------------------
__global__ __launch_bounds__(256) void conv_kernel(
    const ushortT* __restrict__ xr, const float* __restrict__ w,
    const float* __restrict__ b, ushortT* __restrict__ u) {
  int idx = blockIdx.x * blockDim.x + threadIdx.x;  // over B*S*DI/4 = 524288
  int g = idx & 255;                 // d-group (d = 4g)
  int s = (idx >> 8) & (S_LEN - 1);
  int bb = idx >> 18;
  int d = g * 4;
  float4 bias = *(const float4*)&b[d];
  float4 w0 = *(const float4*)&w[(d + 0) * 4];
  float4 w1 = *(const float4*)&w[(d + 1) * 4];
  float4 w2 = *(const float4*)&w[(d + 2) * 4];
  float4 w3 = *(const float4*)&w[(d + 3) * 4];
  float a0 = bias.x, a1 = bias.y, a2 = bias.z, a3 = bias.w;
  const ushortT* xs = xr + (size_t)(bb * S_LEN) * (2 * DI) + d;
#pragma unroll
  for (int k = 0; k < 4; ++k) {
    int si = s - 3 + k;
    if (si >= 0) {
      ushort4 v = *(const ushort4*)&xs[(size_t)si * (2 * DI)];
      float wk0 = ((const float*)&w0)[k], wk1 = ((const float*)&w1)[k];
      float wk2 = ((const float*)&w2)[k], wk3 = ((const float*)&w3)[k];
      a0 = fmaf(b2f(v.x), wk0, a0);
      a1 = fmaf(b2f(v.y), wk1, a1);
      a2 = fmaf(b2f(v.z), wk2, a2);
      a3 = fmaf(b2f(v.w), wk3, a3);
    }
  }
  ushort4 o; o.x = f2b(a0); o.y = f2b(a1); o.z = f2b(a2); o.w = f2b(a3);
  *(ushort4*)&u[(size_t)idx * 4] = o;
}

// ---- prep_bc: per chunk bc: dbl -> dtin, Cb, btr (B^T), G=tril(C.B^T) -------
__global__ __launch_bounds__(256) void prep_bc(
    const float* __restrict__ dbl, ushortT* __restrict__ dtin,
    ushortT* __restrict__ Cb, ushortT* __restrict__ btr,
    ushortT* __restrict__ G) {
  __shared__ ushortT Bl[64][132];  // padded stride vs bank conflicts
  __shared__ ushortT Cl[64][132];
  const int bc = blockIdx.x, t = threadIdx.x;
  // dtin = bf16(dbl[:, 0:32])
  for (int i = 0; i < 8; ++i) {
    int idx = i * 256 + t;
    int row = idx >> 5, col = idx & 31;
    dtin[(size_t)(bc * 64 + row) * 32 + col] =
        f2b(dbl[(size_t)(bc * 64 + row) * 288 + col]);
  }
  // load 64 rows x 256 cols (B|C) fp32, cvt to bf16 in LDS
  for (int i = 0; i < 64; ++i) {
    int idx = i * 256 + t;
    int row = idx >> 8, col = idx & 255;
    float v = dbl[(size_t)(bc * 64 + row) * 288 + 32 + col];
    if (col < 128) Bl[row][col] = f2b(v);
    else Cl[row][col - 128] = f2b(v);
  }
  __syncthreads();
  // Cb global: ushort4 coalesced
  for (int i = 0; i < 8; ++i) {
    int idx4 = i * 256 + t;
    int row = idx4 >> 5, c4 = (idx4 & 31) * 4;
    ushort4 o;
    o.x = Cl[row][c4]; o.y = Cl[row][c4 + 1];
    o.z = Cl[row][c4 + 2]; o.w = Cl[row][c4 + 3];
    *(ushort4*)&Cb[(size_t)(bc * 64 + row) * 128 + c4] = o;
  }
  // btr[bc][n][s] = B[s][n]
  for (int i = 0; i < 32; ++i) {
    int idx = i * 256 + t;
    int n = idx >> 6, s = idx & 63;
    btr[(size_t)bc * 8192 + idx] = Bl[s][n];
  }
  // G = tril(C @ B^T) via MFMA from LDS
  const int l = t & 63, w = t >> 6;
  f32x4 acc[4] = {};
#pragma unroll
  for (int kk = 0; kk < 4; ++kk) {
    short8 a = *(const short8*)&Cl[w * 16 + (l & 15)][kk * 32 + (l >> 4) * 8];
#pragma unroll
    for (int nf = 0; nf < 4; ++nf) {
      short8 bb = *(const short8*)&Bl[nf * 16 + (l & 15)][kk * 32 + (l >> 4) * 8];
      acc[nf] = __builtin_amdgcn_mfma_f32_16x16x32_bf16(a, bb, acc[nf], 0, 0, 0);
    }
  }
#pragma unroll
  for (int nf = 0; nf < 4; ++nf) {
    int s = nf * 16 + (l & 15);
#pragma unroll
    for (int i = 0; i < 4; ++i) {
      int tr = w * 16 + (l >> 4) * 4 + i;
      float v = (s <= tr) ? acc[nf][i] : 0.f;
      G[((size_t)bc * 64 + tr) * 64 + s] = f2b(v);
    }
  }
}

// ---- decay: LDS-tiled cumprod. grid (8 dg, 32 bc), 256 threads --------------
// Reads om[64][128] + u[64][128] tiles (coalesced), cumprod over s (pure
// multiplies from LDS), writes D fp32 + ut (transposed [d][s]) bf16.
__global__ __launch_bounds__(256) void decay_kernel(
    const float* __restrict__ om, const ushortT* __restrict__ u_bf,
    float* __restrict__ D, ushortT* __restrict__ ut) {
  __shared__ float oml[64][128];
  __shared__ ushortT ul[64][128];
  __shared__ ushortT lt[128][66];
  const int t = threadIdx.x;
  const int dg = blockIdx.x, bc = blockIdx.y;
  const int b = bc >> 4, c = bc & 15;
  const size_t rowbase = (size_t)(b * S_LEN + c * CL) * DI + dg * 128;
#pragma unroll
  for (int i = 0; i < 8; ++i) {
    int idx4 = i * 256 + t;            // 2048 float4
    int row = idx4 >> 5, c4 = (idx4 & 31) * 4;
    *(float4*)&oml[row][c4] = *(const float4*)&om[rowbase + (size_t)row * DI + c4];
  }
#pragma unroll
  for (int i = 0; i < 4; ++i) {
    int idx8 = i * 256 + t;            // 1024 x 8 ushorts
    int row = idx8 >> 4, c8 = (idx8 & 15) * 8;
    *(float4*)&ul[row][c8] = *(const float4*)&u_bf[rowbase + (size_t)row * DI + c8];
  }
  __syncthreads();
  if (t < 128) {
    float cum = 1.f;
#pragma unroll 8
    for (int s = 0; s < CL; ++s) {
      cum *= oml[s][t];
      D[rowbase + (size_t)s * DI + t] = cum;
      lt[t][s] = f2b(b2f(ul[s][t]) / cum);
    }
  }
  __syncthreads();
#pragma unroll
  for (int i = 0; i < 8; ++i) {
    int idx4 = i * 256 + t;            // 2048 ushort4
    int r = idx4 >> 4, s4 = (idx4 & 15) * 4;
    ushort4 o;
    o.x = lt[r][s4]; o.y = lt[r][s4 + 1]; o.z = lt[r][s4 + 2]; o.w = lt[r][s4 + 3];
    *(ushort4*)&ut[((size_t)bc * DI + dg * 128 + r) * CL + s4] = o;
  }
}

// ---- Z[bc][d][n] = sum_s ut[d,s] * Btr[n,s]  (bf16 out into zb layout) ------
__global__ __launch_bounds__(256) void gemm_z(
    const ushortT* __restrict__ ut, const ushortT* __restrict__ btr,
    ushortT* __restrict__ zb) {
  __shared__ ushortT As[128 * 32];
  __shared__ ushortT Bs[128 * 32];
  const int tid = threadIdx.x;
  const int l = tid & 63, w = tid >> 6;
  const int wr = w >> 1, wc = w & 1;
  const int bc = blockIdx.z;
  const int b = bc >> 4, c = bc & 15;
  const int bm = blockIdx.y * 128;
  const ushortT* A = ut + (size_t)bc * DI * CL;
  const ushortT* Bt = btr + (size_t)bc * DS * CL;
  const int srow = l >> 2, scol = (l & 3) * 8;
  f32x4 acc[4][4] = {};
  for (int k0 = 0; k0 < CL; k0 += 32) {
#pragma unroll
    for (int j = 0; j < 2; ++j) {
      int sub = w * 2 + j;
      GLOAD16(A + (size_t)(bm + sub * 16 + srow) * CL + k0 + scol, &As[sub * 512]);
      GLOAD16(Bt + (size_t)(sub * 16 + srow) * CL + k0 + scol, &Bs[sub * 512]);
    }
    __syncthreads();
    short8 a[4], bb[4];
#pragma unroll
    for (int m = 0; m < 4; ++m)
      a[m] = *(const short8*)&As[(wr * 64 + m * 16 + (l & 15)) * 32 + (l >> 4) * 8];
#pragma unroll
    for (int n = 0; n < 4; ++n)
      bb[n] = *(const short8*)&Bs[(wc * 64 + n * 16 + (l & 15)) * 32 + (l >> 4) * 8];
#pragma unroll
    for (int m = 0; m < 4; ++m)
#pragma unroll
      for (int n = 0; n < 4; ++n)
        acc[m][n] = __builtin_amdgcn_mfma_f32_16x16x32_bf16(a[m], bb[n], acc[m][n], 0, 0, 0);
    __syncthreads();
  }
#pragma unroll
  for (int m = 0; m < 4; ++m) {
    int d = bm + wr * 64 + m * 16 + (l >> 4) * 4;
#pragma unroll
    for (int n = 0; n < 4; ++n) {
      int gn = wc * 64 + n * 16 + (l & 15);
#pragma unroll
      for (int i = 0; i < 4; ++i)
        zb[(((size_t)(b * DI + d + i)) * NC + c) * 128 + gn] = f2b(acc[m][n][i]);
    }
  }
}

// ---- pass2: h_entry chain over chunks; hstb bf16 = entry state --------------
__global__ __launch_bounds__(256) void scan_pass2(
    const ushortT* __restrict__ zb, const float* __restrict__ D,
    ushortT* __restrict__ hstb) {
  int wid = (blockIdx.x * blockDim.x + threadIdx.x) >> 6;  // 0..2047 = b*DI+d
  int lane = threadIdx.x & 63;
  int b = wid >> 10, d = wid & (DI - 1);
  size_t base = (size_t)wid * NC * 128;
  float h0 = 0.f, h1 = 0.f;
  for (int c = 0; c < NC; ++c) {
    float dend = D[((size_t)(b * S_LEN + c * CL + CL - 1)) * DI + d];
    ushort2 z2 = *(const ushort2*)&zb[base + c * 128 + 2 * lane];
    ushort2 he;
    he.x = f2b(h0); he.y = f2b(h1);
    *(ushort2*)&hstb[base + c * 128 + 2 * lane] = he;
    h0 = dend * (h0 + b2f(z2.x));
    h1 = dend * (h1 + b2f(z2.y));
  }
}

// ---- Y: yr[t,d] = bf16( D[t,d]*( G@ut + Cb@hstb ) + res ) -------------------
__global__ __launch_bounds__(256) void gemm_y(
    const ushortT* __restrict__ G, const ushortT* __restrict__ ut,
    const ushortT* __restrict__ Cb, const ushortT* __restrict__ hstb,
    const float* __restrict__ D, const ushortT* __restrict__ xr_bf,
    ushortT* __restrict__ yr) {
  const int tid = threadIdx.x;
  const int l = tid & 63, w = tid >> 6;
  const int bc = blockIdx.y, d0 = blockIdx.x * 256;
  const int b = bc >> 4, c = bc & 15;
  const int brow = b * S_LEN + c * CL;
  f32x4 acc[4][4] = {};
  // phase 1: K=64 (s): A = G rows, Bt = ut rows
#pragma unroll
  for (int kk = 0; kk < 2; ++kk) {
    short8 a[4], bb[4];
#pragma unroll
    for (int m = 0; m < 4; ++m)
      a[m] = *(const short8*)&G[((size_t)bc * 64 + m * 16 + (l & 15)) * 64 + kk * 32 + (l >> 4) * 8];
#pragma unroll
    for (int n = 0; n < 4; ++n) {
      int d = d0 + w * 64 + n * 16 + (l & 15);
      bb[n] = *(const short8*)&ut[((size_t)bc * DI + d) * CL + kk * 32 + (l >> 4) * 8];
    }
#pragma unroll
    for (int m = 0; m < 4; ++m)
#pragma unroll
      for (int n = 0; n < 4; ++n)
        acc[m][n] = __builtin_amdgcn_mfma_f32_16x16x32_bf16(a[m], bb[n], acc[m][n], 0, 0, 0);
  }
  // phase 2: K=128 (n): A = Cb rows, Bt = hstb rows
#pragma unroll
  for (int kk = 0; kk < 4; ++kk) {
    short8 a[4], bb[4];
#pragma unroll
    for (int m = 0; m < 4; ++m)
      a[m] = *(const short8*)&Cb[((size_t)brow + m * 16 + (l & 15)) * 128 + kk * 32 + (l >> 4) * 8];
#pragma unroll
    for (int n = 0; n < 4; ++n) {
      int d = d0 + w * 64 + n * 16 + (l & 15);
      bb[n] = *(const short8*)&hstb[((size_t)(b * DI + d)) * (NC * 128) + c * 128 + kk * 32 + (l >> 4) * 8];
    }
#pragma unroll
    for (int m = 0; m < 4; ++m)
#pragma unroll
      for (int n = 0; n < 4; ++n)
        acc[m][n] = __builtin_amdgcn_mfma_f32_16x16x32_bf16(a[m], bb[n], acc[m][n], 0, 0, 0);
  }
#pragma unroll
  for (int m = 0; m < 4; ++m) {
#pragma unroll
    for (int n = 0; n < 4; ++n) {
      int d = d0 + w * 64 + n * 16 + (l & 15);
#pragma unroll
      for (int i = 0; i < 4; ++i) {
        int gr = brow + m * 16 + (l >> 4) * 4 + i;
        float Dv = D[(size_t)gr * DI + d];
        float res = b2f(xr_bf[(size_t)gr * 2048 + 1024 + d]);
        yr[(size_t)gr * DI + d] = f2b(acc[m][n][i] * Dv + res);
      }
    }
  }
}

extern "C" void kernel_launch(void* const* d_in, const int* in_sizes, int n_in,
                              void* d_out, int out_size, void* d_ws, size_t ws_size,
                              hipStream_t stream) {
  const float* x      = (const float*)d_in[0];
  const float* W_in   = (const float*)d_in[1];
  const float* conv_w = (const float*)d_in[2];
  const float* conv_b = (const float*)d_in[3];
  const float* W_x    = (const float*)d_in[4];
  const float* W_dt   = (const float*)d_in[5];
  const float* b_dt   = (const float*)d_in[6];
  const float* W_out  = (const float*)d_in[7];
  float* out = (float*)d_out;
  float* ws = (float*)d_ws;

  // workspace (float units); total 13,991,936 floats = 56 MB.
  // Alias: om (fp32 [2048,1024]) <- zb region; om is produced at step 6, dead
  // after step 7 (decay); zb first written at step 8. Lifetimes disjoint.
  ushortT* xr_bf = (ushortT*)ws;                  // [2048,2048] bf16
  ushortT* u_bf  = (ushortT*)(ws + 2097152);      // [2048,1024] bf16
  float*   dbl   = ws + 3145728;                  // [2048,288] fp32
  float*   Dc    = ws + 3735552;                  // [2048,1024] fp32
  ushortT* ut    = (ushortT*)(ws + 5832704);      // [32,1024,64] bf16
  ushortT* zb    = (ushortT*)(ws + 6881280);      // [2048,16,128] bf16
  ushortT* hstb  = (ushortT*)(ws + 8978432);      // [2048,16,128] bf16
  ushortT* Cb    = (ushortT*)(ws + 11075584);     // [2048,128] bf16
  ushortT* btr   = (ushortT*)(ws + 11206656);     // [32,128,64] bf16
  ushortT* G     = (ushortT*)(ws + 11337728);     // [32,64,64] bf16
  ushortT* x_bf  = (ushortT*)(ws + 11403264);     // [2048,512] bf16
  ushortT* Wt_in = (ushortT*)(ws + 11927552);     // [2048,512] bf16
  ushortT* Wt_x  = (ushortT*)(ws + 12451840);     // [384,1024] bf16
  ushortT* Wt_out= (ushortT*)(ws + 12648448);     // [512,1024] bf16
  ushortT* yr_bf = (ushortT*)(ws + 12910592);     // [2048,1024] bf16
  ushortT* Wt_dt = (ushortT*)(ws + 13959168);     // [1024,32] bf16
  ushortT* dtin  = (ushortT*)(ws + 13975552);     // [2048,32] bf16
  float*   om    = (float*)zb;                    // alias (see above)

  dim3 blk(256);
  // 1) weight transposes + x cvt
  prep_all<<<2976, dim3(32, 8), 0, stream>>>(W_in, W_x, W_out, W_dt, x,
                                             Wt_in, Wt_x, Wt_out, Wt_dt, x_bf);
  // 2) in-proj: xr = x @ W_in (bf16)  M=2048 N=2048 K=512; grid 16x16 flat
  gemm_mfma<1><<<256, blk, 0, stream>>>(x_bf, Wt_in, nullptr, xr_bf, 2 * DI, DM, 2 * DI, 16);
  // 3) conv -> u (bf16)
  conv_kernel<<<2048, blk, 0, stream>>>(xr_bf, conv_w, conv_b, u_bf);
  // 4) x-proj: dbl = u @ W_x (fp32)   M=2048 N=288 K=1024; grid 3x16 flat
  gemm_mfma<0><<<48, blk, 0, stream>>>(u_bf, Wt_x, nullptr, dbl, DTR + 2 * DS, DI, DTR + 2 * DS, 3);
  // 5) per-chunk prep: dtin, Cb, btr, G
  prep_bc<<<32, blk, 0, stream>>>(dbl, dtin, Cb, btr, G);
  // 6) dt-proj + softplus/clip -> om = 1-dt (fp32)  M=2048 N=1024 K=32
  gemm_mfma<3><<<128, blk, 0, stream>>>(dtin, Wt_dt, b_dt, om, DI, DTR, DI, 8);
  // 7) decay: cumprod D + ut
  decay_kernel<<<dim3(8, 32), blk, 0, stream>>>(om, u_bf, Dc, ut);
  // 8) Z = ut @ Btr^T per chunk -> zb
  gemm_z<<<dim3(1, 8, 32), blk, 0, stream>>>(ut, btr, zb);
  // 9) chunk-boundary combine -> hstb (entry states, bf16)
  scan_pass2<<<512, blk, 0, stream>>>(zb, Dc, hstb);
  // 10) Y = D*(G@ut + C@h_entry) + res -> yr_bf
  gemm_y<<<dim3(4, 32), blk, 0, stream>>>(G, ut, Cb, hstb, Dc, xr_bf, yr_bf);
  // 11) out-proj: out = yr @ W_out (fp32)  M=2048 N=512 K=1024; grid 4x16 flat
  gemm_mfma<0><<<64, blk, 0, stream>>>(yr_bf, Wt_out, nullptr, out, DM, DI, DM, 4);
}

// Round 9
// 153.352 us; speedup vs baseline: 1.1867x; 1.1366x over previous
//
#include <hip/hip_runtime.h>
#include <math.h>

#define S_LEN 1024
#define BATCH 2
#define DM 512
#define DI 1024
#define DS 128
#define DTR 32
#define CL 64            // chunk length
#define NC (S_LEN / CL)  // 16 chunks

typedef unsigned short ushortT;
typedef __attribute__((ext_vector_type(8))) short short8;
typedef __attribute__((ext_vector_type(4))) float f32x4;

__device__ __forceinline__ ushortT f2b(float f) {
  unsigned u = __builtin_bit_cast(unsigned, f);
  unsigned r = (u + 0x7fff + ((u >> 16) & 1)) >> 16;  // RNE
  return (ushortT)r;
}
__device__ __forceinline__ float b2f(ushortT h) {
  return __builtin_bit_cast(float, (unsigned)h << 16);
}

#define GLOAD16(g, l)                                                     \
  __builtin_amdgcn_global_load_lds(                                       \
      (const __attribute__((address_space(1))) void*)(g),                 \
      (__attribute__((address_space(3))) void*)(l), 16, 0, 0)

// ---- bf16 MFMA GEMM: C[M,N] = A[M,K] @ Bt[Npad,K]^T -------------------------
// 128x128 tile, 256 threads = 4 waves (2x2). Flat grid + XCD swizzle.
// MODE 0: fp32 out; 1: bf16 out.
template<int MODE>
__global__ __launch_bounds__(256) void gemm_mfma(
    const ushortT* __restrict__ A, const ushortT* __restrict__ Bt,
    void* __restrict__ Cout, int N, int K, int ldc, int nbx) {
  __shared__ ushortT As[128 * 32];
  __shared__ ushortT Bs[128 * 32];
  const int nwg = gridDim.x;
  const int bid = blockIdx.x;
  const int flat = (bid & 7) * (nwg >> 3) + (bid >> 3);  // XCD-contiguous
  const int bxi = flat % nbx, byi = flat / nbx;
  const int bm = byi * 128, bn = bxi * 128;
  const int tid = threadIdx.x;
  const int l = tid & 63, w = tid >> 6;
  const int wr = w >> 1, wc = w & 1;
  const int srow = l >> 2, scol = (l & 3) * 8;
  f32x4 acc[4][4] = {};
  for (int k0 = 0; k0 < K; k0 += 32) {
#pragma unroll
    for (int j = 0; j < 2; ++j) {
      int sub = w * 2 + j;
      const ushortT* gA = A + (size_t)(bm + sub * 16 + srow) * K + k0 + scol;
      GLOAD16(gA, &As[sub * 512]);
      const ushortT* gB = Bt + (size_t)(bn + sub * 16 + srow) * K + k0 + scol;
      GLOAD16(gB, &Bs[sub * 512]);
    }
    __syncthreads();
    short8 a[4], b[4];
#pragma unroll
    for (int m = 0; m < 4; ++m)
      a[m] = *(const short8*)&As[(wr * 64 + m * 16 + (l & 15)) * 32 + (l >> 4) * 8];
#pragma unroll
    for (int n = 0; n < 4; ++n)
      b[n] = *(const short8*)&Bs[(wc * 64 + n * 16 + (l & 15)) * 32 + (l >> 4) * 8];
#pragma unroll
    for (int m = 0; m < 4; ++m)
#pragma unroll
      for (int n = 0; n < 4; ++n)
        acc[m][n] = __builtin_amdgcn_mfma_f32_16x16x32_bf16(a[m], b[n], acc[m][n], 0, 0, 0);
    __syncthreads();
  }
#pragma unroll
  for (int m = 0; m < 4; ++m) {
    int grow = bm + wr * 64 + m * 16 + (l >> 4) * 4;
#pragma unroll
    for (int n = 0; n < 4; ++n) {
      int gcol = bn + wc * 64 + n * 16 + (l & 15);
      if (gcol >= N) continue;
#pragma unroll
      for (int i = 0; i < 4; ++i) {
        float v = acc[m][n][i];
        if (MODE == 1)
          ((ushortT*)Cout)[(size_t)(grow + i) * ldc + gcol] = f2b(v);
        else
          ((float*)Cout)[(size_t)(grow + i) * ldc + gcol] = v;
      }
    }
  }
}

// ---- prep_all: weight transposes (fp32->bf16, [K,N]->[Npad,K]) + x cvt ------
// blocks [0,1024) W_in; [1024,1408) W_x(pad 384); [1408,1920) W_out;
// [1920,2944) x -> x_bf.
__global__ __launch_bounds__(256) void prep_all(
    const float* __restrict__ W_in, const float* __restrict__ W_x,
    const float* __restrict__ W_out, const float* __restrict__ x,
    ushortT* __restrict__ Wt_in, ushortT* __restrict__ Wt_x,
    ushortT* __restrict__ Wt_out, ushortT* __restrict__ x_bf) {
  __shared__ float tb[32][33];
  int bid = blockIdx.x;
  int tx = threadIdx.x, ty = threadIdx.y;  // (32,8)
  const float* in; ushortT* out; int K, N, bx, by;
  if (bid < 1024)      { in = W_in;  out = Wt_in;  K = 512;  N = 2048; bx = bid & 63; by = bid >> 6; }
  else if (bid < 1408) { int t2 = bid - 1024; in = W_x;   out = Wt_x;   K = 1024; N = 288;  bx = t2 % 12; by = t2 / 12; }
  else if (bid < 1920) { int t2 = bid - 1408; in = W_out; out = Wt_out; K = 1024; N = 512;  bx = t2 % 16; by = t2 / 16; }
  else {
    int i = (bid - 1920) * 256 + ty * 32 + tx;
    float4 v = ((const float4*)x)[i];
    ushort4 o; o.x = f2b(v.x); o.y = f2b(v.y); o.z = f2b(v.z); o.w = f2b(v.w);
    ((ushort4*)x_bf)[i] = o;
    return;
  }
  int n0 = bx * 32, k0 = by * 32;
  if (n0 < N) {
#pragma unroll
    for (int i = 0; i < 4; ++i)
      tb[ty + 8 * i][tx] = in[(size_t)(k0 + ty + 8 * i) * N + n0 + tx];
    __syncthreads();
#pragma unroll
    for (int i = 0; i < 4; ++i)
      out[(size_t)(n0 + ty + 8 * i) * K + k0 + tx] = f2b(tb[tx][ty + 8 * i]);
  } else {
#pragma unroll
    for (int i = 0; i < 4; ++i)
      out[(size_t)(n0 + ty + 8 * i) * K + k0 + tx] = 0;
  }
}

// ---- depthwise causal conv, 4 d per thread (ushort4) ------------------------
__global__ __launch_bounds__(256) void conv_kernel(
    const ushortT* __restrict__ xr, const float* __restrict__ w,
    const float* __restrict__ b, ushortT* __restrict__ u) {
  int idx = blockIdx.x * blockDim.x + threadIdx.x;  // over B*S*DI/4 = 524288
  int g = idx & 255;                 // d-group (d = 4g)
  int s = (idx >> 8) & (S_LEN - 1);
  int bb = idx >> 18;
  int d = g * 4;
  float4 bias = *(const float4*)&b[d];
  float4 w0 = *(const float4*)&w[(d + 0) * 4];
  float4 w1 = *(const float4*)&w[(d + 1) * 4];
  float4 w2 = *(const float4*)&w[(d + 2) * 4];
  float4 w3 = *(const float4*)&w[(d + 3) * 4];
  float a0 = bias.x, a1 = bias.y, a2 = bias.z, a3 = bias.w;
  const ushortT* xs = xr + (size_t)(bb * S_LEN) * (2 * DI) + d;
#pragma unroll
  for (int k = 0; k < 4; ++k) {
    int si = s - 3 + k;
    if (si >= 0) {
      ushort4 v = *(const ushort4*)&xs[(size_t)si * (2 * DI)];
      float wk0 = ((const float*)&w0)[k], wk1 = ((const float*)&w1)[k];
      float wk2 = ((const float*)&w2)[k], wk3 = ((const float*)&w3)[k];
      a0 = fmaf(b2f(v.x), wk0, a0);
      a1 = fmaf(b2f(v.y), wk1, a1);
      a2 = fmaf(b2f(v.z), wk2, a2);
      a3 = fmaf(b2f(v.w), wk3, a3);
    }
  }
  ushort4 o; o.x = f2b(a0); o.y = f2b(a1); o.z = f2b(a2); o.w = f2b(a3);
  *(ushort4*)&u[(size_t)idx * 4] = o;
}

// ---- megachunk: per (dg, bc): dt-proj + softplus/clip + cumprod + ut +
//      Z = ut @ B^T (MFMA) ; dg==0 additionally Cb + G = tril(C @ B^T).
// Replaces prep_bc + dt-GEMM + decay + gemm_z. One block per CU (119 KB LDS).
__global__ __launch_bounds__(256) void megachunk(
    const float* __restrict__ dbl, const float* __restrict__ W_dt,
    const float* __restrict__ b_dt, const ushortT* __restrict__ u_bf,
    float* __restrict__ D, ushortT* __restrict__ ut,
    ushortT* __restrict__ zb, ushortT* __restrict__ Cb,
    ushortT* __restrict__ G) {
  __shared__ ushortT Btl[128][72];   // B^T[n][s]
  __shared__ float   Dl[128][67];    // om -> cumprod D, [d][s]
  __shared__ ushortT utl[128][72];   // ut[d][s]
  __shared__ float   dtl[64][33];    // dbl[:,0:32] slice
  __shared__ ushortT Wl[32][136];    // W_dt slice bf16 [k][d]
  __shared__ ushortT Bl[64][132];    // B rows (dg==0 only)
  __shared__ ushortT Cl[64][132];    // C rows (dg==0 only)
  const int t = threadIdx.x;
  const int dg = blockIdx.x, bc = blockIdx.y;
  const int b = bc >> 4, c = bc & 15;
  const size_t rowbase = (size_t)(b * S_LEN + c * CL) * DI + dg * 128;

  // phase 0: stage inputs
  for (int j = 0; j < 16; ++j) {           // W_dt 32x128 slice
    int idx = j * 256 + t; int d = idx & 127, k = idx >> 7;
    Wl[k][d] = f2b(W_dt[(size_t)k * DI + dg * 128 + d]);
  }
  for (int j = 0; j < 8; ++j) {            // dtl 64x32
    int idx = j * 256 + t; int k = idx & 31, s = idx >> 5;
    dtl[s][k] = dbl[(size_t)(bc * 64 + s) * 288 + k];
  }
  for (int j = 0; j < 32; ++j) {           // Btl: B^T 128x64
    int idx = j * 256 + t; int n = idx & 127, s = idx >> 7;
    Btl[n][s] = f2b(dbl[(size_t)(bc * 64 + s) * 288 + 32 + n]);
  }
  if (dg == 0) {
    for (int j = 0; j < 64; ++j) {         // B|C rows for G and Cb
      int idx = j * 256 + t; int col = idx & 255, s = idx >> 8;
      float v = dbl[(size_t)(bc * 64 + s) * 288 + 32 + col];
      if (col < 128) Bl[s][col] = f2b(v); else Cl[s][col - 128] = f2b(v);
    }
  }
  __syncthreads();

  // phase 1: dt-proj + softplus/clip -> om in Dl[d][s]
  {
    int d = t & 127, shalf = t >> 7;
    float bias = b_dt[dg * 128 + d] + 1e-4f;
#pragma unroll 4
    for (int j = 0; j < 32; ++j) {
      int s = j * 2 + shalf;
      float acc = bias;
#pragma unroll
      for (int k = 0; k < 32; ++k) acc = fmaf(dtl[s][k], b2f(Wl[k][d]), acc);
      acc = (acc > 20.f) ? acc : log1pf(expf(acc));
      acc = fminf(fmaxf(acc, 0.001f), 0.1f);
      Dl[d][s] = 1.f - acc;
    }
  }
  __syncthreads();

  // phase 2: cumprod in place (pure multiplies from LDS)
  if (t < 128) {
    float cum = 1.f;
#pragma unroll 8
    for (int s = 0; s < CL; ++s) { cum *= Dl[t][s]; Dl[t][s] = cum; }
  }
  __syncthreads();

  // phase 3: D global (float4 coalesced) + ut build from u
  for (int j = 0; j < 8; ++j) {
    int idx4 = j * 256 + t; int d4 = (idx4 & 31) * 4, s = idx4 >> 5;
    float4 v;
    v.x = Dl[d4][s]; v.y = Dl[d4 + 1][s]; v.z = Dl[d4 + 2][s]; v.w = Dl[d4 + 3][s];
    *(float4*)&D[rowbase + (size_t)s * DI + d4] = v;
  }
  for (int j = 0; j < 4; ++j) {
    int idx8 = j * 256 + t; int d8 = (idx8 & 15) * 8, s = idx8 >> 4;
    float4 raw = *(const float4*)&u_bf[rowbase + (size_t)s * DI + d8];
    const ushortT* up = (const ushortT*)&raw;
#pragma unroll
    for (int k = 0; k < 8; ++k)
      utl[d8 + k][s] = f2b(b2f(up[k]) / Dl[d8 + k][s]);
  }
  __syncthreads();

  // phase 4: ut global write (rows d, 128B each)
  for (int j = 0; j < 4; ++j) {
    int idx8 = j * 256 + t; int d = idx8 >> 3, s8 = (idx8 & 7) * 8;
    float4 v; ushortT* vp = (ushortT*)&v;
#pragma unroll
    for (int k = 0; k < 8; ++k) vp[k] = utl[d][s8 + k];
    *(float4*)&ut[((size_t)bc * DI + dg * 128 + d) * CL + s8] = v;
  }

  // phase 5: Z = utl @ Btl^T (128d x 128n, K=64) via MFMA
  const int l = t & 63, w = t >> 6;
  const int wr = w >> 1, wc = w & 1;
  {
    f32x4 acc[4][4] = {};
#pragma unroll
    for (int kk = 0; kk < 2; ++kk) {
      short8 a[4], bb[4];
#pragma unroll
      for (int m = 0; m < 4; ++m)
        a[m] = *(const short8*)&utl[wr * 64 + m * 16 + (l & 15)][kk * 32 + (l >> 4) * 8];
#pragma unroll
      for (int n = 0; n < 4; ++n)
        bb[n] = *(const short8*)&Btl[wc * 64 + n * 16 + (l & 15)][kk * 32 + (l >> 4) * 8];
#pragma unroll
      for (int m = 0; m < 4; ++m)
#pragma unroll
        for (int n = 0; n < 4; ++n)
          acc[m][n] = __builtin_amdgcn_mfma_f32_16x16x32_bf16(a[m], bb[n], acc[m][n], 0, 0, 0);
    }
#pragma unroll
    for (int m = 0; m < 4; ++m) {
      int d = dg * 128 + wr * 64 + m * 16 + (l >> 4) * 4;
#pragma unroll
      for (int n = 0; n < 4; ++n) {
        int gn = wc * 64 + n * 16 + (l & 15);
#pragma unroll
        for (int i = 0; i < 4; ++i)
          zb[(((size_t)(b * DI + d + i)) * NC + c) * 128 + gn] = f2b(acc[m][n][i]);
      }
    }
  }

  // phase 6 (dg==0): Cb global + G = tril(C @ B^T)
  if (dg == 0) {
    for (int i = 0; i < 8; ++i) {
      int idx4 = i * 256 + t;
      int row = idx4 >> 5, c4 = (idx4 & 31) * 4;
      ushort4 o;
      o.x = Cl[row][c4]; o.y = Cl[row][c4 + 1];
      o.z = Cl[row][c4 + 2]; o.w = Cl[row][c4 + 3];
      *(ushort4*)&Cb[(size_t)(bc * 64 + row) * 128 + c4] = o;
    }
    f32x4 gacc[4] = {};
#pragma unroll
    for (int kk = 0; kk < 4; ++kk) {
      short8 a = *(const short8*)&Cl[w * 16 + (l & 15)][kk * 32 + (l >> 4) * 8];
#pragma unroll
      for (int nf = 0; nf < 4; ++nf) {
        short8 bb = *(const short8*)&Bl[nf * 16 + (l & 15)][kk * 32 + (l >> 4) * 8];
        gacc[nf] = __builtin_amdgcn_mfma_f32_16x16x32_bf16(a, bb, gacc[nf], 0, 0, 0);
      }
    }
#pragma unroll
    for (int nf = 0; nf < 4; ++nf) {
      int s = nf * 16 + (l & 15);
#pragma unroll
      for (int i = 0; i < 4; ++i) {
        int tr = w * 16 + (l >> 4) * 4 + i;
        float v = (s <= tr) ? gacc[nf][i] : 0.f;
        G[((size_t)bc * 64 + tr) * 64 + s] = f2b(v);
      }
    }
  }
}

// ---- pass2: h_entry chain over chunks; hstb bf16 = entry state --------------
__global__ __launch_bounds__(256) void scan_pass2(
    const ushortT* __restrict__ zb, const float* __restrict__ D,
    ushortT* __restrict__ hstb) {
  int wid = (blockIdx.x * blockDim.x + threadIdx.x) >> 6;  // 0..2047 = b*DI+d
  int lane = threadIdx.x & 63;
  int b = wid >> 10, d = wid & (DI - 1);
  size_t base = (size_t)wid * NC * 128;
  float h0 = 0.f, h1 = 0.f;
  for (int c = 0; c < NC; ++c) {
    float dend = D[((size_t)(b * S_LEN + c * CL + CL - 1)) * DI + d];
    ushort2 z2 = *(const ushort2*)&zb[base + c * 128 + 2 * lane];
    ushort2 he;
    he.x = f2b(h0); he.y = f2b(h1);
    *(ushort2*)&hstb[base + c * 128 + 2 * lane] = he;
    h0 = dend * (h0 + b2f(z2.x));
    h1 = dend * (h1 + b2f(z2.y));
  }
}

// ---- Y: yr[t,d] = bf16( D[t,d]*( G@ut + Cb@hstb ) + res ) -------------------
__global__ __launch_bounds__(256) void gemm_y(
    const ushortT* __restrict__ G, const ushortT* __restrict__ ut,
    const ushortT* __restrict__ Cb, const ushortT* __restrict__ hstb,
    const float* __restrict__ D, const ushortT* __restrict__ xr_bf,
    ushortT* __restrict__ yr) {
  const int tid = threadIdx.x;
  const int l = tid & 63, w = tid >> 6;
  const int bc = blockIdx.y, d0 = blockIdx.x * 256;
  const int b = bc >> 4, c = bc & 15;
  const int brow = b * S_LEN + c * CL;
  f32x4 acc[4][4] = {};
  // phase 1: K=64 (s): A = G rows, Bt = ut rows
#pragma unroll
  for (int kk = 0; kk < 2; ++kk) {
    short8 a[4], bb[4];
#pragma unroll
    for (int m = 0; m < 4; ++m)
      a[m] = *(const short8*)&G[((size_t)bc * 64 + m * 16 + (l & 15)) * 64 + kk * 32 + (l >> 4) * 8];
#pragma unroll
    for (int n = 0; n < 4; ++n) {
      int d = d0 + w * 64 + n * 16 + (l & 15);
      bb[n] = *(const short8*)&ut[((size_t)bc * DI + d) * CL + kk * 32 + (l >> 4) * 8];
    }
#pragma unroll
    for (int m = 0; m < 4; ++m)
#pragma unroll
      for (int n = 0; n < 4; ++n)
        acc[m][n] = __builtin_amdgcn_mfma_f32_16x16x32_bf16(a[m], bb[n], acc[m][n], 0, 0, 0);
  }
  // phase 2: K=128 (n): A = Cb rows, Bt = hstb rows
#pragma unroll
  for (int kk = 0; kk < 4; ++kk) {
    short8 a[4], bb[4];
#pragma unroll
    for (int m = 0; m < 4; ++m)
      a[m] = *(const short8*)&Cb[((size_t)brow + m * 16 + (l & 15)) * 128 + kk * 32 + (l >> 4) * 8];
#pragma unroll
    for (int n = 0; n < 4; ++n) {
      int d = d0 + w * 64 + n * 16 + (l & 15);
      bb[n] = *(const short8*)&hstb[((size_t)(b * DI + d)) * (NC * 128) + c * 128 + kk * 32 + (l >> 4) * 8];
    }
#pragma unroll
    for (int m = 0; m < 4; ++m)
#pragma unroll
      for (int n = 0; n < 4; ++n)
        acc[m][n] = __builtin_amdgcn_mfma_f32_16x16x32_bf16(a[m], bb[n], acc[m][n], 0, 0, 0);
  }
#pragma unroll
  for (int m = 0; m < 4; ++m) {
#pragma unroll
    for (int n = 0; n < 4; ++n) {
      int d = d0 + w * 64 + n * 16 + (l & 15);
#pragma unroll
      for (int i = 0; i < 4; ++i) {
        int gr = brow + m * 16 + (l >> 4) * 4 + i;
        float Dv = D[(size_t)gr * DI + d];
        float res = b2f(xr_bf[(size_t)gr * 2048 + 1024 + d]);
        yr[(size_t)gr * DI + d] = f2b(acc[m][n][i] * Dv + res);
      }
    }
  }
}

extern "C" void kernel_launch(void* const* d_in, const int* in_sizes, int n_in,
                              void* d_out, int out_size, void* d_ws, size_t ws_size,
                              hipStream_t stream) {
  const float* x      = (const float*)d_in[0];
  const float* W_in   = (const float*)d_in[1];
  const float* conv_w = (const float*)d_in[2];
  const float* conv_b = (const float*)d_in[3];
  const float* W_x    = (const float*)d_in[4];
  const float* W_dt   = (const float*)d_in[5];
  const float* b_dt   = (const float*)d_in[6];
  const float* W_out  = (const float*)d_in[7];
  float* out = (float*)d_out;
  float* ws = (float*)d_ws;

  // workspace (float units), all disjoint; total 13,828,096 floats = 55.3 MB
  ushortT* xr_bf = (ushortT*)ws;                  // [2048,2048] bf16
  ushortT* u_bf  = (ushortT*)(ws + 2097152);      // [2048,1024] bf16
  float*   dbl   = ws + 3145728;                  // [2048,288] fp32
  float*   Dc    = ws + 3735552;                  // [2048,1024] fp32
  ushortT* ut    = (ushortT*)(ws + 5832704);      // [32,1024,64] bf16
  ushortT* zb    = (ushortT*)(ws + 6881280);      // [2048,16,128] bf16
  ushortT* hstb  = (ushortT*)(ws + 8978432);      // [2048,16,128] bf16
  ushortT* Cb    = (ushortT*)(ws + 11075584);     // [2048,128] bf16
  ushortT* G     = (ushortT*)(ws + 11206656);     // [32,64,64] bf16
  ushortT* x_bf  = (ushortT*)(ws + 11272192);     // [2048,512] bf16
  ushortT* Wt_in = (ushortT*)(ws + 11796480);     // [2048,512] bf16
  ushortT* Wt_x  = (ushortT*)(ws + 12320768);     // [384,1024] bf16
  ushortT* Wt_out= (ushortT*)(ws + 12517376);     // [512,1024] bf16
  ushortT* yr_bf = (ushortT*)(ws + 12779520);     // [2048,1024] bf16

  dim3 blk(256);
  // 1) weight transposes + x cvt
  prep_all<<<2944, dim3(32, 8), 0, stream>>>(W_in, W_x, W_out, x,
                                             Wt_in, Wt_x, Wt_out, x_bf);
  // 2) in-proj: xr = x @ W_in (bf16)  M=2048 N=2048 K=512; grid 16x16 flat
  gemm_mfma<1><<<256, blk, 0, stream>>>(x_bf, Wt_in, xr_bf, 2 * DI, DM, 2 * DI, 16);
  // 3) conv -> u (bf16)
  conv_kernel<<<2048, blk, 0, stream>>>(xr_bf, conv_w, conv_b, u_bf);
  // 4) x-proj: dbl = u @ W_x (fp32)   M=2048 N=288 K=1024; grid 3x16 flat
  gemm_mfma<0><<<48, blk, 0, stream>>>(u_bf, Wt_x, dbl, DTR + 2 * DS, DI, DTR + 2 * DS, 3);
  // 5) megachunk: dt-proj + decay + ut + Z (+ Cb, G on dg==0)
  megachunk<<<dim3(8, 32), blk, 0, stream>>>(dbl, W_dt, b_dt, u_bf, Dc, ut, zb, Cb, G);
  // 6) chunk-boundary combine -> hstb (entry states, bf16)
  scan_pass2<<<512, blk, 0, stream>>>(zb, Dc, hstb);
  // 7) Y = D*(G@ut + C@h_entry) + res -> yr_bf
  gemm_y<<<dim3(4, 32), blk, 0, stream>>>(G, ut, Cb, hstb, Dc, xr_bf, yr_bf);
  // 8) out-proj: out = yr @ W_out (fp32)  M=2048 N=512 K=1024; grid 4x16 flat
  gemm_mfma<0><<<64, blk, 0, stream>>>(yr_bf, Wt_out, out, DM, DI, DM, 4);
}

// Round 10
// 119.078 us; speedup vs baseline: 1.5282x; 1.2878x over previous
//
#include <hip/hip_runtime.h>
#include <math.h>

#define S_LEN 1024
#define BATCH 2
#define DM 512
#define DI 1024
#define DS 128
#define DTR 32
#define CL 64            // chunk length
#define NC (S_LEN / CL)  // 16 chunks

typedef unsigned short ushortT;
typedef __attribute__((ext_vector_type(8))) short short8;
typedef __attribute__((ext_vector_type(4))) float f32x4;

__device__ __forceinline__ ushortT f2b(float f) {
  unsigned u = __builtin_bit_cast(unsigned, f);
  unsigned r = (u + 0x7fff + ((u >> 16) & 1)) >> 16;  // RNE
  return (ushortT)r;
}
__device__ __forceinline__ float b2f(ushortT h) {
  return __builtin_bit_cast(float, (unsigned)h << 16);
}

#define GLOAD16(g, l)                                                     \
  __builtin_amdgcn_global_load_lds(                                       \
      (const __attribute__((address_space(1))) void*)(g),                 \
      (__attribute__((address_space(3))) void*)(l), 16, 0, 0)

// ---- bf16 MFMA GEMM: C[M,N] = A[M,K] @ Bt[Npad,K]^T -------------------------
// 128x128 tile, 256 threads = 4 waves (2x2). Flat grid + XCD swizzle.
// MODE 0: fp32 out; 1: bf16 out.
template<int MODE>
__global__ __launch_bounds__(256) void gemm_mfma(
    const ushortT* __restrict__ A, const ushortT* __restrict__ Bt,
    void* __restrict__ Cout, int N, int K, int ldc, int nbx) {
  __shared__ ushortT As[128 * 32];
  __shared__ ushortT Bs[128 * 32];
  const int nwg = gridDim.x;
  const int bid = blockIdx.x;
  const int flat = (bid & 7) * (nwg >> 3) + (bid >> 3);  // XCD-contiguous
  const int bxi = flat % nbx, byi = flat / nbx;
  const int bm = byi * 128, bn = bxi * 128;
  const int tid = threadIdx.x;
  const int l = tid & 63, w = tid >> 6;
  const int wr = w >> 1, wc = w & 1;
  const int srow = l >> 2, scol = (l & 3) * 8;
  f32x4 acc[4][4] = {};
  for (int k0 = 0; k0 < K; k0 += 32) {
#pragma unroll
    for (int j = 0; j < 2; ++j) {
      int sub = w * 2 + j;
      const ushortT* gA = A + (size_t)(bm + sub * 16 + srow) * K + k0 + scol;
      GLOAD16(gA, &As[sub * 512]);
      const ushortT* gB = Bt + (size_t)(bn + sub * 16 + srow) * K + k0 + scol;
      GLOAD16(gB, &Bs[sub * 512]);
    }
    __syncthreads();
    short8 a[4], b[4];
#pragma unroll
    for (int m = 0; m < 4; ++m)
      a[m] = *(const short8*)&As[(wr * 64 + m * 16 + (l & 15)) * 32 + (l >> 4) * 8];
#pragma unroll
    for (int n = 0; n < 4; ++n)
      b[n] = *(const short8*)&Bs[(wc * 64 + n * 16 + (l & 15)) * 32 + (l >> 4) * 8];
#pragma unroll
    for (int m = 0; m < 4; ++m)
#pragma unroll
      for (int n = 0; n < 4; ++n)
        acc[m][n] = __builtin_amdgcn_mfma_f32_16x16x32_bf16(a[m], b[n], acc[m][n], 0, 0, 0);
    __syncthreads();
  }
#pragma unroll
  for (int m = 0; m < 4; ++m) {
    int grow = bm + wr * 64 + m * 16 + (l >> 4) * 4;
#pragma unroll
    for (int n = 0; n < 4; ++n) {
      int gcol = bn + wc * 64 + n * 16 + (l & 15);
      if (gcol >= N) continue;
#pragma unroll
      for (int i = 0; i < 4; ++i) {
        float v = acc[m][n][i];
        if (MODE == 1)
          ((ushortT*)Cout)[(size_t)(grow + i) * ldc + gcol] = f2b(v);
        else
          ((float*)Cout)[(size_t)(grow + i) * ldc + gcol] = v;
      }
    }
  }
}

// ---- prep_all: weight transposes (fp32->bf16, [K,N]->[Npad,K]) + x cvt ------
__global__ __launch_bounds__(256) void prep_all(
    const float* __restrict__ W_in, const float* __restrict__ W_x,
    const float* __restrict__ W_out, const float* __restrict__ x,
    ushortT* __restrict__ Wt_in, ushortT* __restrict__ Wt_x,
    ushortT* __restrict__ Wt_out, ushortT* __restrict__ x_bf) {
  __shared__ float tb[32][33];
  int bid = blockIdx.x;
  int tx = threadIdx.x, ty = threadIdx.y;  // (32,8)
  const float* in; ushortT* out; int K, N, bx, by;
  if (bid < 1024)      { in = W_in;  out = Wt_in;  K = 512;  N = 2048; bx = bid & 63; by = bid >> 6; }
  else if (bid < 1408) { int t2 = bid - 1024; in = W_x;   out = Wt_x;   K = 1024; N = 288;  bx = t2 % 12; by = t2 / 12; }
  else if (bid < 1920) { int t2 = bid - 1408; in = W_out; out = Wt_out; K = 1024; N = 512;  bx = t2 % 16; by = t2 / 16; }
  else {
    int i = (bid - 1920) * 256 + ty * 32 + tx;
    float4 v = ((const float4*)x)[i];
    ushort4 o; o.x = f2b(v.x); o.y = f2b(v.y); o.z = f2b(v.z); o.w = f2b(v.w);
    ((ushort4*)x_bf)[i] = o;
    return;
  }
  int n0 = bx * 32, k0 = by * 32;
  if (n0 < N) {
#pragma unroll
    for (int i = 0; i < 4; ++i)
      tb[ty + 8 * i][tx] = in[(size_t)(k0 + ty + 8 * i) * N + n0 + tx];
    __syncthreads();
#pragma unroll
    for (int i = 0; i < 4; ++i)
      out[(size_t)(n0 + ty + 8 * i) * K + k0 + tx] = f2b(tb[tx][ty + 8 * i]);
  } else {
#pragma unroll
    for (int i = 0; i < 4; ++i)
      out[(size_t)(n0 + ty + 8 * i) * K + k0 + tx] = 0;
  }
}

// ---- depthwise causal conv, 4 d per thread (ushort4) ------------------------
__global__ __launch_bounds__(256) void conv_kernel(
    const ushortT* __restrict__ xr, const float* __restrict__ w,
    const float* __restrict__ b, ushortT* __restrict__ u) {
  int idx = blockIdx.x * blockDim.x + threadIdx.x;  // over B*S*DI/4 = 524288
  int g = idx & 255;
  int s = (idx >> 8) & (S_LEN - 1);
  int bb = idx >> 18;
  int d = g * 4;
  float4 bias = *(const float4*)&b[d];
  float4 w0 = *(const float4*)&w[(d + 0) * 4];
  float4 w1 = *(const float4*)&w[(d + 1) * 4];
  float4 w2 = *(const float4*)&w[(d + 2) * 4];
  float4 w3 = *(const float4*)&w[(d + 3) * 4];
  float a0 = bias.x, a1 = bias.y, a2 = bias.z, a3 = bias.w;
  const ushortT* xs = xr + (size_t)(bb * S_LEN) * (2 * DI) + d;
#pragma unroll
  for (int k = 0; k < 4; ++k) {
    int si = s - 3 + k;
    if (si >= 0) {
      ushort4 v = *(const ushort4*)&xs[(size_t)si * (2 * DI)];
      float wk0 = ((const float*)&w0)[k], wk1 = ((const float*)&w1)[k];
      float wk2 = ((const float*)&w2)[k], wk3 = ((const float*)&w3)[k];
      a0 = fmaf(b2f(v.x), wk0, a0);
      a1 = fmaf(b2f(v.y), wk1, a1);
      a2 = fmaf(b2f(v.z), wk2, a2);
      a3 = fmaf(b2f(v.w), wk3, a3);
    }
  }
  ushort4 o; o.x = f2b(a0); o.y = f2b(a1); o.z = f2b(a2); o.w = f2b(a3);
  *(ushort4*)&u[(size_t)idx * 4] = o;
}

// ---- megachunk: per (dg, bc) 64-d slice: dt-proj + softplus/clip + cumprod
//      + ut + Z = ut @ B^T. 58 KB LDS -> 2 blocks/CU. ------------------------
__global__ __launch_bounds__(256) void megachunk(
    const float* __restrict__ dbl, const float* __restrict__ W_dt,
    const float* __restrict__ b_dt, const ushortT* __restrict__ u_bf,
    float* __restrict__ D, ushortT* __restrict__ ut,
    ushortT* __restrict__ zb) {
  __shared__ ushortT Btl[128][72];   // B^T[n][s]
  __shared__ float   Dl[64][66];     // om -> cumprod D, [d][s]
  __shared__ ushortT utl[64][72];    // ut[d][s]
  __shared__ float   dtl[64][36];    // dbl[:,0:32]
  __shared__ ushortT Wl[32][68];     // W_dt slice bf16 [k][d]
  const int t = threadIdx.x;
  const int dg = blockIdx.x, bc = blockIdx.y;   // dg 0..15 (64-d slices)
  const int b = bc >> 4, c = bc & 15;
  const size_t rowbase = (size_t)(b * S_LEN + c * CL) * DI + dg * 64;

  // stage Btl (float4 over n), dtl (float4), Wl (float2)
#pragma unroll
  for (int j = 0; j < 8; ++j) {
    int idx4 = j * 256 + t;                       // 2048
    int s = idx4 >> 5, n4 = (idx4 & 31) * 4;
    float4 v = *(const float4*)&dbl[(size_t)(bc * 64 + s) * 288 + 32 + n4];
    Btl[n4][s] = f2b(v.x); Btl[n4 + 1][s] = f2b(v.y);
    Btl[n4 + 2][s] = f2b(v.z); Btl[n4 + 3][s] = f2b(v.w);
  }
#pragma unroll
  for (int j = 0; j < 2; ++j) {
    int idx4 = j * 256 + t;                       // 512
    int s = idx4 >> 3, k4 = (idx4 & 7) * 4;
    *(float4*)&dtl[s][k4] = *(const float4*)&dbl[(size_t)(bc * 64 + s) * 288 + k4];
  }
#pragma unroll
  for (int j = 0; j < 4; ++j) {
    int idx2 = j * 256 + t;                       // 1024
    int k = idx2 >> 5, d2 = (idx2 & 31) * 2;
    float2 v = *(const float2*)&W_dt[(size_t)k * DI + dg * 64 + d2];
    Wl[k][d2] = f2b(v.x); Wl[k][d2 + 1] = f2b(v.y);
  }
  __syncthreads();

  // dt-proj: wave w owns s-quarter, lane = d. W hoisted to registers.
  {
    int d = t & 63, sq = t >> 6;
    float wreg[32];
#pragma unroll
    for (int k = 0; k < 32; ++k) wreg[k] = b2f(Wl[k][d]);
    float bias = b_dt[dg * 64 + d] + 1e-4f;
#pragma unroll 4
    for (int j = 0; j < 16; ++j) {
      int s = sq * 16 + j;
      float acc = bias;
#pragma unroll
      for (int k = 0; k < 32; ++k) acc = fmaf(dtl[s][k], wreg[k], acc);
      acc = (acc > 20.f) ? acc : log1pf(expf(acc));
      acc = fminf(fmaxf(acc, 0.001f), 0.1f);
      Dl[d][s] = 1.f - acc;
    }
  }
  __syncthreads();

  // cumprod (t<64, pure LDS multiplies; reads independent -> pipelined)
  if (t < 64) {
    float cum = 1.f;
#pragma unroll 16
    for (int s = 0; s < CL; ++s) { cum *= Dl[t][s]; Dl[t][s] = cum; }
  }
  __syncthreads();

  // D global write [s][d] float4
#pragma unroll
  for (int j = 0; j < 4; ++j) {
    int idx4 = j * 256 + t;                       // 1024
    int s = idx4 >> 4, d4 = (idx4 & 15) * 4;
    float4 v;
    v.x = Dl[d4][s]; v.y = Dl[d4 + 1][s]; v.z = Dl[d4 + 2][s]; v.w = Dl[d4 + 3][s];
    *(float4*)&D[rowbase + (size_t)s * DI + d4] = v;
  }
  // ut build: u float4 (8 bf16) / Dl -> utl[d][s]
#pragma unroll
  for (int j = 0; j < 2; ++j) {
    int idx8 = j * 256 + t;                       // 512
    int s = idx8 >> 3, d8 = (idx8 & 7) * 8;
    float4 raw = *(const float4*)&u_bf[rowbase + (size_t)s * DI + d8];
    const ushortT* up = (const ushortT*)&raw;
#pragma unroll
    for (int k = 0; k < 8; ++k)
      utl[d8 + k][s] = f2b(b2f(up[k]) / Dl[d8 + k][s]);
  }
  __syncthreads();

  // ut global write (rows d)
#pragma unroll
  for (int j = 0; j < 2; ++j) {
    int idx8 = j * 256 + t;                       // 512
    int d = idx8 >> 3, s8 = (idx8 & 7) * 8;
    float4 v; ushortT* vp = (ushortT*)&v;
#pragma unroll
    for (int k = 0; k < 8; ++k) vp[k] = utl[d][s8 + k];
    *(float4*)&ut[((size_t)bc * DI + dg * 64 + d) * CL + s8] = v;
  }

  // Z = utl @ Btl^T : wave w -> 16 d-rows, 8 n-frags, K=64
  {
    const int l = t & 63, w = t >> 6;
    f32x4 acc[8] = {};
#pragma unroll
    for (int kk = 0; kk < 2; ++kk) {
      short8 a = *(const short8*)&utl[w * 16 + (l & 15)][kk * 32 + (l >> 4) * 8];
#pragma unroll
      for (int n = 0; n < 8; ++n) {
        short8 bb = *(const short8*)&Btl[n * 16 + (l & 15)][kk * 32 + (l >> 4) * 8];
        acc[n] = __builtin_amdgcn_mfma_f32_16x16x32_bf16(a, bb, acc[n], 0, 0, 0);
      }
    }
#pragma unroll
    for (int n = 0; n < 8; ++n) {
      int gn = n * 16 + (l & 15);
#pragma unroll
      for (int i = 0; i < 4; ++i) {
        int d = dg * 64 + w * 16 + (l >> 4) * 4 + i;
        zb[(((size_t)(b * DI + d)) * NC + c) * 128 + gn] = f2b(acc[n][i]);
      }
    }
  }
}

// ---- pass2: h_entry chain over chunks; hstb bf16 = entry state --------------
__global__ __launch_bounds__(256) void scan_pass2(
    const ushortT* __restrict__ zb, const float* __restrict__ D,
    ushortT* __restrict__ hstb) {
  int wid = (blockIdx.x * blockDim.x + threadIdx.x) >> 6;  // 0..2047 = b*DI+d
  int lane = threadIdx.x & 63;
  int b = wid >> 10, d = wid & (DI - 1);
  size_t base = (size_t)wid * NC * 128;
  float h0 = 0.f, h1 = 0.f;
  for (int c = 0; c < NC; ++c) {
    float dend = D[((size_t)(b * S_LEN + c * CL + CL - 1)) * DI + d];
    ushort2 z2 = *(const ushort2*)&zb[base + c * 128 + 2 * lane];
    ushort2 he;
    he.x = f2b(h0); he.y = f2b(h1);
    *(ushort2*)&hstb[base + c * 128 + 2 * lane] = he;
    h0 = dend * (h0 + b2f(z2.x));
    h1 = dend * (h1 + b2f(z2.y));
  }
}

// ---- Y: stage B,C from dbl; G = tril(C.B^T) in LDS; then
//      yr[t,d] = bf16( D[t,d]*( G@ut + C@hstb ) + res ) ----------------------
__global__ __launch_bounds__(256) void gemm_y(
    const float* __restrict__ dbl, const ushortT* __restrict__ ut,
    const ushortT* __restrict__ hstb, const float* __restrict__ D,
    const ushortT* __restrict__ xr_bf, ushortT* __restrict__ yr) {
  __shared__ ushortT Bl[64][136];
  __shared__ ushortT Cl[64][136];
  __shared__ ushortT Gl[64][72];
  const int tid = threadIdx.x;
  const int l = tid & 63, w = tid >> 6;
  const int bc = blockIdx.y, d0 = blockIdx.x * 256;
  const int b = bc >> 4, c = bc & 15;
  const int brow = b * S_LEN + c * CL;
  // stage B|C rows (float4)
#pragma unroll
  for (int j = 0; j < 16; ++j) {
    int idx4 = j * 256 + tid;                     // 4096
    int row = idx4 >> 6, c4 = (idx4 & 63) * 4;
    float4 v = *(const float4*)&dbl[(size_t)(bc * 64 + row) * 288 + 32 + c4];
    ushortT o0 = f2b(v.x), o1 = f2b(v.y), o2 = f2b(v.z), o3 = f2b(v.w);
    if (c4 < 128) { Bl[row][c4] = o0; Bl[row][c4+1] = o1; Bl[row][c4+2] = o2; Bl[row][c4+3] = o3; }
    else { int cc = c4 - 128; Cl[row][cc] = o0; Cl[row][cc+1] = o1; Cl[row][cc+2] = o2; Cl[row][cc+3] = o3; }
  }
  __syncthreads();
  // G = tril(C @ B^T) -> Gl
  {
    f32x4 gacc[4] = {};
#pragma unroll
    for (int kk = 0; kk < 4; ++kk) {
      short8 a = *(const short8*)&Cl[w * 16 + (l & 15)][kk * 32 + (l >> 4) * 8];
#pragma unroll
      for (int nf = 0; nf < 4; ++nf) {
        short8 bb = *(const short8*)&Bl[nf * 16 + (l & 15)][kk * 32 + (l >> 4) * 8];
        gacc[nf] = __builtin_amdgcn_mfma_f32_16x16x32_bf16(a, bb, gacc[nf], 0, 0, 0);
      }
    }
#pragma unroll
    for (int nf = 0; nf < 4; ++nf) {
      int s = nf * 16 + (l & 15);
#pragma unroll
      for (int i = 0; i < 4; ++i) {
        int tr = w * 16 + (l >> 4) * 4 + i;
        Gl[tr][s] = f2b((s <= tr) ? gacc[nf][i] : 0.f);
      }
    }
  }
  __syncthreads();
  f32x4 acc[4][4] = {};
  // phase 1: K=64 (s): A = Gl rows, B = ut rows (global)
#pragma unroll
  for (int kk = 0; kk < 2; ++kk) {
    short8 a[4], bb[4];
#pragma unroll
    for (int m = 0; m < 4; ++m)
      a[m] = *(const short8*)&Gl[m * 16 + (l & 15)][kk * 32 + (l >> 4) * 8];
#pragma unroll
    for (int n = 0; n < 4; ++n) {
      int d = d0 + w * 64 + n * 16 + (l & 15);
      bb[n] = *(const short8*)&ut[((size_t)bc * DI + d) * CL + kk * 32 + (l >> 4) * 8];
    }
#pragma unroll
    for (int m = 0; m < 4; ++m)
#pragma unroll
      for (int n = 0; n < 4; ++n)
        acc[m][n] = __builtin_amdgcn_mfma_f32_16x16x32_bf16(a[m], bb[n], acc[m][n], 0, 0, 0);
  }
  // phase 2: K=128 (n): A = Cl rows, B = hstb rows (global)
#pragma unroll
  for (int kk = 0; kk < 4; ++kk) {
    short8 a[4], bb[4];
#pragma unroll
    for (int m = 0; m < 4; ++m)
      a[m] = *(const short8*)&Cl[m * 16 + (l & 15)][kk * 32 + (l >> 4) * 8];
#pragma unroll
    for (int n = 0; n < 4; ++n) {
      int d = d0 + w * 64 + n * 16 + (l & 15);
      bb[n] = *(const short8*)&hstb[((size_t)(b * DI + d)) * (NC * 128) + c * 128 + kk * 32 + (l >> 4) * 8];
    }
#pragma unroll
    for (int m = 0; m < 4; ++m)
#pragma unroll
      for (int n = 0; n < 4; ++n)
        acc[m][n] = __builtin_amdgcn_mfma_f32_16x16x32_bf16(a[m], bb[n], acc[m][n], 0, 0, 0);
  }
#pragma unroll
  for (int m = 0; m < 4; ++m) {
#pragma unroll
    for (int n = 0; n < 4; ++n) {
      int d = d0 + w * 64 + n * 16 + (l & 15);
#pragma unroll
      for (int i = 0; i < 4; ++i) {
        int gr = brow + m * 16 + (l >> 4) * 4 + i;
        float Dv = D[(size_t)gr * DI + d];
        float res = b2f(xr_bf[(size_t)gr * 2048 + 1024 + d]);
        yr[(size_t)gr * DI + d] = f2b(acc[m][n][i] * Dv + res);
      }
    }
  }
}

extern "C" void kernel_launch(void* const* d_in, const int* in_sizes, int n_in,
                              void* d_out, int out_size, void* d_ws, size_t ws_size,
                              hipStream_t stream) {
  const float* x      = (const float*)d_in[0];
  const float* W_in   = (const float*)d_in[1];
  const float* conv_w = (const float*)d_in[2];
  const float* conv_b = (const float*)d_in[3];
  const float* W_x    = (const float*)d_in[4];
  const float* W_dt   = (const float*)d_in[5];
  const float* b_dt   = (const float*)d_in[6];
  const float* W_out  = (const float*)d_in[7];
  float* out = (float*)d_out;
  float* ws = (float*)d_ws;

  // workspace (float units), all disjoint; total 13,631,488 floats = 54.5 MB
  ushortT* xr_bf = (ushortT*)ws;                  // [2048,2048] bf16
  ushortT* u_bf  = (ushortT*)(ws + 2097152);      // [2048,1024] bf16
  float*   dbl   = ws + 3145728;                  // [2048,288] fp32
  float*   Dc    = ws + 3735552;                  // [2048,1024] fp32
  ushortT* ut    = (ushortT*)(ws + 5832704);      // [32,1024,64] bf16
  ushortT* zb    = (ushortT*)(ws + 6881280);      // [2048,16,128] bf16
  ushortT* hstb  = (ushortT*)(ws + 8978432);      // [2048,16,128] bf16
  ushortT* x_bf  = (ushortT*)(ws + 11075584);     // [2048,512] bf16
  ushortT* Wt_in = (ushortT*)(ws + 11599872);     // [2048,512] bf16
  ushortT* Wt_x  = (ushortT*)(ws + 12124160);     // [384,1024] bf16
  ushortT* Wt_out= (ushortT*)(ws + 12320768);     // [512,1024] bf16
  ushortT* yr_bf = (ushortT*)(ws + 12582912);     // [2048,1024] bf16

  dim3 blk(256);
  // 1) weight transposes + x cvt
  prep_all<<<2944, dim3(32, 8), 0, stream>>>(W_in, W_x, W_out, x,
                                             Wt_in, Wt_x, Wt_out, x_bf);
  // 2) in-proj: xr = x @ W_in (bf16)  M=2048 N=2048 K=512; grid 16x16 flat
  gemm_mfma<1><<<256, blk, 0, stream>>>(x_bf, Wt_in, xr_bf, 2 * DI, DM, 2 * DI, 16);
  // 3) conv -> u (bf16)
  conv_kernel<<<2048, blk, 0, stream>>>(xr_bf, conv_w, conv_b, u_bf);
  // 4) x-proj: dbl = u @ W_x (fp32)   M=2048 N=288 K=1024; grid 3x16 flat
  gemm_mfma<0><<<48, blk, 0, stream>>>(u_bf, Wt_x, dbl, DTR + 2 * DS, DI, DTR + 2 * DS, 3);
  // 5) megachunk: dt-proj + decay + ut + Z  (512 blocks, 2/CU)
  megachunk<<<dim3(16, 32), blk, 0, stream>>>(dbl, W_dt, b_dt, u_bf, Dc, ut, zb);
  // 6) chunk-boundary combine -> hstb (entry states, bf16)
  scan_pass2<<<512, blk, 0, stream>>>(zb, Dc, hstb);
  // 7) Y = D*(G@ut + C@h_entry) + res -> yr_bf  (G computed in-block)
  gemm_y<<<dim3(4, 32), blk, 0, stream>>>(dbl, ut, hstb, Dc, xr_bf, yr_bf);
  // 8) out-proj: out = yr @ W_out (fp32)  M=2048 N=512 K=1024; grid 4x16 flat
  gemm_mfma<0><<<64, blk, 0, stream>>>(yr_bf, Wt_out, out, DM, DI, DM, 4);
}

// Round 11
// 101.731 us; speedup vs baseline: 1.7888x; 1.1705x over previous
//
#include <hip/hip_runtime.h>
#include <math.h>

#define S_LEN 1024
#define BATCH 2
#define DM 512
#define DI 1024
#define DS 128
#define DTR 32
#define CL 64            // chunk length
#define NC (S_LEN / CL)  // 16 chunks

typedef unsigned short ushortT;
typedef __attribute__((ext_vector_type(8))) short short8;
typedef __attribute__((ext_vector_type(4))) float f32x4;

__device__ __forceinline__ ushortT f2b(float f) {
  unsigned u = __builtin_bit_cast(unsigned, f);
  unsigned r = (u + 0x7fff + ((u >> 16) & 1)) >> 16;  // RNE
  return (ushortT)r;
}
__device__ __forceinline__ float b2f(ushortT h) {
  return __builtin_bit_cast(float, (unsigned)h << 16);
}

#define GLOAD16(g, l)                                                     \
  __builtin_amdgcn_global_load_lds(                                       \
      (const __attribute__((address_space(1))) void*)(g),                 \
      (__attribute__((address_space(3))) void*)(l), 16, 0, 0)

// ---- bf16 MFMA GEMM (128x128 tile): used for in-proj ------------------------
template<int MODE>
__global__ __launch_bounds__(256) void gemm_mfma(
    const ushortT* __restrict__ A, const ushortT* __restrict__ Bt,
    void* __restrict__ Cout, int N, int K, int ldc, int nbx) {
  __shared__ ushortT As[128 * 32];
  __shared__ ushortT Bs[128 * 32];
  const int nwg = gridDim.x;
  const int bid = blockIdx.x;
  const int flat = (bid & 7) * (nwg >> 3) + (bid >> 3);  // XCD-contiguous
  const int bxi = flat % nbx, byi = flat / nbx;
  const int bm = byi * 128, bn = bxi * 128;
  const int tid = threadIdx.x;
  const int l = tid & 63, w = tid >> 6;
  const int wr = w >> 1, wc = w & 1;
  const int srow = l >> 2, scol = (l & 3) * 8;
  f32x4 acc[4][4] = {};
  for (int k0 = 0; k0 < K; k0 += 32) {
#pragma unroll
    for (int j = 0; j < 2; ++j) {
      int sub = w * 2 + j;
      const ushortT* gA = A + (size_t)(bm + sub * 16 + srow) * K + k0 + scol;
      GLOAD16(gA, &As[sub * 512]);
      const ushortT* gB = Bt + (size_t)(bn + sub * 16 + srow) * K + k0 + scol;
      GLOAD16(gB, &Bs[sub * 512]);
    }
    __syncthreads();
    short8 a[4], b[4];
#pragma unroll
    for (int m = 0; m < 4; ++m)
      a[m] = *(const short8*)&As[(wr * 64 + m * 16 + (l & 15)) * 32 + (l >> 4) * 8];
#pragma unroll
    for (int n = 0; n < 4; ++n)
      b[n] = *(const short8*)&Bs[(wc * 64 + n * 16 + (l & 15)) * 32 + (l >> 4) * 8];
#pragma unroll
    for (int m = 0; m < 4; ++m)
#pragma unroll
      for (int n = 0; n < 4; ++n)
        acc[m][n] = __builtin_amdgcn_mfma_f32_16x16x32_bf16(a[m], b[n], acc[m][n], 0, 0, 0);
    __syncthreads();
  }
#pragma unroll
  for (int m = 0; m < 4; ++m) {
    int grow = bm + wr * 64 + m * 16 + (l >> 4) * 4;
#pragma unroll
    for (int n = 0; n < 4; ++n) {
      int gcol = bn + wc * 64 + n * 16 + (l & 15);
      if (gcol >= N) continue;
#pragma unroll
      for (int i = 0; i < 4; ++i) {
        float v = acc[m][n][i];
        if (MODE == 1)
          ((ushortT*)Cout)[(size_t)(grow + i) * ldc + gcol] = f2b(v);
        else
          ((float*)Cout)[(size_t)(grow + i) * ldc + gcol] = v;
      }
    }
  }
}

// ---- gemm64: 64x64 tile, 4 waves (2x2, each 32x32). For grid-starved GEMMs --
template<int MODE>
__global__ __launch_bounds__(256) void gemm64(
    const ushortT* __restrict__ A, const ushortT* __restrict__ Bt,
    void* __restrict__ Cout, int N, int K, int ldc, int nbx) {
  __shared__ ushortT As[64 * 32];
  __shared__ ushortT Bs[64 * 32];
  const int nwg = gridDim.x;
  const int bid = blockIdx.x;
  const int flat = (bid & 7) * (nwg >> 3) + (bid >> 3);
  const int bxi = flat % nbx, byi = flat / nbx;
  const int bm = byi * 64, bn = bxi * 64;
  const int tid = threadIdx.x;
  const int l = tid & 63, w = tid >> 6;
  const int wr = w >> 1, wc = w & 1;
  const int srow = tid >> 2, scol = (tid & 3) * 8;  // 256 thr: 64 rows x 32 cols
  f32x4 acc[2][2] = {};
  for (int k0 = 0; k0 < K; k0 += 32) {
    GLOAD16(A + (size_t)(bm + srow) * K + k0 + scol, &As[(size_t)tid * 8]);
    GLOAD16(Bt + (size_t)(bn + srow) * K + k0 + scol, &Bs[(size_t)tid * 8]);
    __syncthreads();
    short8 a[2], b[2];
#pragma unroll
    for (int m = 0; m < 2; ++m)
      a[m] = *(const short8*)&As[(wr * 32 + m * 16 + (l & 15)) * 32 + (l >> 4) * 8];
#pragma unroll
    for (int n = 0; n < 2; ++n)
      b[n] = *(const short8*)&Bs[(wc * 32 + n * 16 + (l & 15)) * 32 + (l >> 4) * 8];
#pragma unroll
    for (int m = 0; m < 2; ++m)
#pragma unroll
      for (int n = 0; n < 2; ++n)
        acc[m][n] = __builtin_amdgcn_mfma_f32_16x16x32_bf16(a[m], b[n], acc[m][n], 0, 0, 0);
    __syncthreads();
  }
#pragma unroll
  for (int m = 0; m < 2; ++m) {
    int grow = bm + wr * 32 + m * 16 + (l >> 4) * 4;
#pragma unroll
    for (int n = 0; n < 2; ++n) {
      int gcol = bn + wc * 32 + n * 16 + (l & 15);
      if (gcol >= N) continue;
#pragma unroll
      for (int i = 0; i < 4; ++i) {
        float v = acc[m][n][i];
        if (MODE == 1)
          ((ushortT*)Cout)[(size_t)(grow + i) * ldc + gcol] = f2b(v);
        else
          ((float*)Cout)[(size_t)(grow + i) * ldc + gcol] = v;
      }
    }
  }
}

// ---- prep_all: weight transposes (fp32->bf16, [K,N]->[Npad,K]) + x cvt ------
__global__ __launch_bounds__(256) void prep_all(
    const float* __restrict__ W_in, const float* __restrict__ W_x,
    const float* __restrict__ W_out, const float* __restrict__ x,
    ushortT* __restrict__ Wt_in, ushortT* __restrict__ Wt_x,
    ushortT* __restrict__ Wt_out, ushortT* __restrict__ x_bf) {
  __shared__ float tb[32][33];
  int bid = blockIdx.x;
  int tx = threadIdx.x, ty = threadIdx.y;  // (32,8)
  const float* in; ushortT* out; int K, N, bx, by;
  if (bid < 1024)      { in = W_in;  out = Wt_in;  K = 512;  N = 2048; bx = bid & 63; by = bid >> 6; }
  else if (bid < 1408) { int t2 = bid - 1024; in = W_x;   out = Wt_x;   K = 1024; N = 288;  bx = t2 % 12; by = t2 / 12; }
  else if (bid < 1920) { int t2 = bid - 1408; in = W_out; out = Wt_out; K = 1024; N = 512;  bx = t2 % 16; by = t2 / 16; }
  else {
    int i = (bid - 1920) * 256 + ty * 32 + tx;
    float4 v = ((const float4*)x)[i];
    ushort4 o; o.x = f2b(v.x); o.y = f2b(v.y); o.z = f2b(v.z); o.w = f2b(v.w);
    ((ushort4*)x_bf)[i] = o;
    return;
  }
  int n0 = bx * 32, k0 = by * 32;
  if (n0 < N) {
#pragma unroll
    for (int i = 0; i < 4; ++i)
      tb[ty + 8 * i][tx] = in[(size_t)(k0 + ty + 8 * i) * N + n0 + tx];
    __syncthreads();
#pragma unroll
    for (int i = 0; i < 4; ++i)
      out[(size_t)(n0 + ty + 8 * i) * K + k0 + tx] = f2b(tb[tx][ty + 8 * i]);
  } else {
#pragma unroll
    for (int i = 0; i < 4; ++i)
      out[(size_t)(n0 + ty + 8 * i) * K + k0 + tx] = 0;
  }
}

// ---- depthwise causal conv, 4 d per thread (ushort4) ------------------------
__global__ __launch_bounds__(256) void conv_kernel(
    const ushortT* __restrict__ xr, const float* __restrict__ w,
    const float* __restrict__ b, ushortT* __restrict__ u) {
  int idx = blockIdx.x * blockDim.x + threadIdx.x;
  int g = idx & 255;
  int s = (idx >> 8) & (S_LEN - 1);
  int bb = idx >> 18;
  int d = g * 4;
  float4 bias = *(const float4*)&b[d];
  float4 w0 = *(const float4*)&w[(d + 0) * 4];
  float4 w1 = *(const float4*)&w[(d + 1) * 4];
  float4 w2 = *(const float4*)&w[(d + 2) * 4];
  float4 w3 = *(const float4*)&w[(d + 3) * 4];
  float a0 = bias.x, a1 = bias.y, a2 = bias.z, a3 = bias.w;
  const ushortT* xs = xr + (size_t)(bb * S_LEN) * (2 * DI) + d;
#pragma unroll
  for (int k = 0; k < 4; ++k) {
    int si = s - 3 + k;
    if (si >= 0) {
      ushort4 v = *(const ushort4*)&xs[(size_t)si * (2 * DI)];
      float wk0 = ((const float*)&w0)[k], wk1 = ((const float*)&w1)[k];
      float wk2 = ((const float*)&w2)[k], wk3 = ((const float*)&w3)[k];
      a0 = fmaf(b2f(v.x), wk0, a0);
      a1 = fmaf(b2f(v.y), wk1, a1);
      a2 = fmaf(b2f(v.z), wk2, a2);
      a3 = fmaf(b2f(v.w), wk3, a3);
    }
  }
  ushort4 o; o.x = f2b(a0); o.y = f2b(a1); o.z = f2b(a2); o.w = f2b(a3);
  *(ushort4*)&u[(size_t)idx * 4] = o;
}

// ---- megachunk: per (dg, bc) 64-d slice: dt-proj + softplus/clip + cumprod
//      + ut + Z = ut @ B^T. 58 KB LDS -> 2 blocks/CU. ------------------------
__global__ __launch_bounds__(256) void megachunk(
    const float* __restrict__ dbl, const float* __restrict__ W_dt,
    const float* __restrict__ b_dt, const ushortT* __restrict__ u_bf,
    float* __restrict__ D, ushortT* __restrict__ ut,
    ushortT* __restrict__ zb) {
  __shared__ ushortT Btl[128][72];   // B^T[n][s]
  __shared__ float   Dl[64][66];     // om -> cumprod D, [d][s]
  __shared__ ushortT utl[64][72];    // ut[d][s]
  __shared__ float   dtl[64][36];    // dbl[:,0:32]
  __shared__ ushortT Wl[32][68];     // W_dt slice bf16 [k][d]
  const int t = threadIdx.x;
  const int dg = blockIdx.x, bc = blockIdx.y;
  const int b = bc >> 4, c = bc & 15;
  const size_t rowbase = (size_t)(b * S_LEN + c * CL) * DI + dg * 64;

#pragma unroll
  for (int j = 0; j < 8; ++j) {
    int idx4 = j * 256 + t;
    int s = idx4 >> 5, n4 = (idx4 & 31) * 4;
    float4 v = *(const float4*)&dbl[(size_t)(bc * 64 + s) * 288 + 32 + n4];
    Btl[n4][s] = f2b(v.x); Btl[n4 + 1][s] = f2b(v.y);
    Btl[n4 + 2][s] = f2b(v.z); Btl[n4 + 3][s] = f2b(v.w);
  }
#pragma unroll
  for (int j = 0; j < 2; ++j) {
    int idx4 = j * 256 + t;
    int s = idx4 >> 3, k4 = (idx4 & 7) * 4;
    *(float4*)&dtl[s][k4] = *(const float4*)&dbl[(size_t)(bc * 64 + s) * 288 + k4];
  }
#pragma unroll
  for (int j = 0; j < 4; ++j) {
    int idx2 = j * 256 + t;
    int k = idx2 >> 5, d2 = (idx2 & 31) * 2;
    float2 v = *(const float2*)&W_dt[(size_t)k * DI + dg * 64 + d2];
    Wl[k][d2] = f2b(v.x); Wl[k][d2 + 1] = f2b(v.y);
  }
  __syncthreads();

  {
    int d = t & 63, sq = t >> 6;
    float wreg[32];
#pragma unroll
    for (int k = 0; k < 32; ++k) wreg[k] = b2f(Wl[k][d]);
    float bias = b_dt[dg * 64 + d] + 1e-4f;
#pragma unroll 4
    for (int j = 0; j < 16; ++j) {
      int s = sq * 16 + j;
      float acc = bias;
#pragma unroll
      for (int k = 0; k < 32; ++k) acc = fmaf(dtl[s][k], wreg[k], acc);
      acc = (acc > 20.f) ? acc : log1pf(expf(acc));
      acc = fminf(fmaxf(acc, 0.001f), 0.1f);
      Dl[d][s] = 1.f - acc;
    }
  }
  __syncthreads();

  if (t < 64) {
    float cum = 1.f;
#pragma unroll 16
    for (int s = 0; s < CL; ++s) { cum *= Dl[t][s]; Dl[t][s] = cum; }
  }
  __syncthreads();

#pragma unroll
  for (int j = 0; j < 4; ++j) {
    int idx4 = j * 256 + t;
    int s = idx4 >> 4, d4 = (idx4 & 15) * 4;
    float4 v;
    v.x = Dl[d4][s]; v.y = Dl[d4 + 1][s]; v.z = Dl[d4 + 2][s]; v.w = Dl[d4 + 3][s];
    *(float4*)&D[rowbase + (size_t)s * DI + d4] = v;
  }
#pragma unroll
  for (int j = 0; j < 2; ++j) {
    int idx8 = j * 256 + t;
    int s = idx8 >> 3, d8 = (idx8 & 7) * 8;
    float4 raw = *(const float4*)&u_bf[rowbase + (size_t)s * DI + d8];
    const ushortT* up = (const ushortT*)&raw;
#pragma unroll
    for (int k = 0; k < 8; ++k)
      utl[d8 + k][s] = f2b(b2f(up[k]) / Dl[d8 + k][s]);
  }
  __syncthreads();

#pragma unroll
  for (int j = 0; j < 2; ++j) {
    int idx8 = j * 256 + t;
    int d = idx8 >> 3, s8 = (idx8 & 7) * 8;
    float4 v; ushortT* vp = (ushortT*)&v;
#pragma unroll
    for (int k = 0; k < 8; ++k) vp[k] = utl[d][s8 + k];
    *(float4*)&ut[((size_t)bc * DI + dg * 64 + d) * CL + s8] = v;
  }

  {
    const int l = t & 63, w = t >> 6;
    f32x4 acc[8] = {};
#pragma unroll
    for (int kk = 0; kk < 2; ++kk) {
      short8 a = *(const short8*)&utl[w * 16 + (l & 15)][kk * 32 + (l >> 4) * 8];
#pragma unroll
      for (int n = 0; n < 8; ++n) {
        short8 bb = *(const short8*)&Btl[n * 16 + (l & 15)][kk * 32 + (l >> 4) * 8];
        acc[n] = __builtin_amdgcn_mfma_f32_16x16x32_bf16(a, bb, acc[n], 0, 0, 0);
      }
    }
#pragma unroll
    for (int n = 0; n < 8; ++n) {
      int gn = n * 16 + (l & 15);
#pragma unroll
      for (int i = 0; i < 4; ++i) {
        int d = dg * 64 + w * 16 + (l >> 4) * 4 + i;
        zb[(((size_t)(b * DI + d)) * NC + c) * 128 + gn] = f2b(acc[n][i]);
      }
    }
  }
}

// ---- pass2: h_entry chain over chunks; unrolled so loads hoist --------------
__global__ __launch_bounds__(256) void scan_pass2(
    const ushortT* __restrict__ zb, const float* __restrict__ D,
    ushortT* __restrict__ hstb) {
  int wid = (blockIdx.x * blockDim.x + threadIdx.x) >> 6;  // 0..2047 = b*DI+d
  int lane = threadIdx.x & 63;
  int b = wid >> 10, d = wid & (DI - 1);
  size_t base = (size_t)wid * NC * 128;
  float h0 = 0.f, h1 = 0.f;
#pragma unroll
  for (int c = 0; c < NC; ++c) {
    float dend = D[((size_t)(b * S_LEN + c * CL + CL - 1)) * DI + d];
    ushort2 z2 = *(const ushort2*)&zb[base + c * 128 + 2 * lane];
    ushort2 he;
    he.x = f2b(h0); he.y = f2b(h1);
    *(ushort2*)&hstb[base + c * 128 + 2 * lane] = he;
    h0 = dend * (h0 + b2f(z2.x));
    h1 = dend * (h1 + b2f(z2.y));
  }
}

// ---- Y (64-d blocks): stage B,C; G = tril(C.B^T); 
//      yr[t,d] = bf16( D[t,d]*( G@ut + C@hstb ) + res ) ----------------------
__global__ __launch_bounds__(256) void gemm_y(
    const float* __restrict__ dbl, const ushortT* __restrict__ ut,
    const ushortT* __restrict__ hstb, const float* __restrict__ D,
    const ushortT* __restrict__ xr_bf, ushortT* __restrict__ yr) {
  __shared__ ushortT Bl[64][136];
  __shared__ ushortT Cl[64][136];
  __shared__ ushortT Gl[64][72];
  const int tid = threadIdx.x;
  const int l = tid & 63, w = tid >> 6;
  const int bc = blockIdx.y, d0 = blockIdx.x * 64;
  const int b = bc >> 4, c = bc & 15;
  const int brow = b * S_LEN + c * CL;
  // stage B|C rows (float4)
#pragma unroll
  for (int j = 0; j < 16; ++j) {
    int idx4 = j * 256 + tid;
    int row = idx4 >> 6, c4 = (idx4 & 63) * 4;
    float4 v = *(const float4*)&dbl[(size_t)(bc * 64 + row) * 288 + 32 + c4];
    ushortT o0 = f2b(v.x), o1 = f2b(v.y), o2 = f2b(v.z), o3 = f2b(v.w);
    if (c4 < 128) { Bl[row][c4] = o0; Bl[row][c4+1] = o1; Bl[row][c4+2] = o2; Bl[row][c4+3] = o3; }
    else { int cc = c4 - 128; Cl[row][cc] = o0; Cl[row][cc+1] = o1; Cl[row][cc+2] = o2; Cl[row][cc+3] = o3; }
  }
  __syncthreads();
  // G rows w*16..+16 = tril(Cl @ Bl^T)
  {
    f32x4 gacc[4] = {};
#pragma unroll
    for (int kk = 0; kk < 4; ++kk) {
      short8 a = *(const short8*)&Cl[w * 16 + (l & 15)][kk * 32 + (l >> 4) * 8];
#pragma unroll
      for (int nf = 0; nf < 4; ++nf) {
        short8 bb = *(const short8*)&Bl[nf * 16 + (l & 15)][kk * 32 + (l >> 4) * 8];
        gacc[nf] = __builtin_amdgcn_mfma_f32_16x16x32_bf16(a, bb, gacc[nf], 0, 0, 0);
      }
    }
#pragma unroll
    for (int nf = 0; nf < 4; ++nf) {
      int s = nf * 16 + (l & 15);
#pragma unroll
      for (int i = 0; i < 4; ++i) {
        int tr = w * 16 + (l >> 4) * 4 + i;
        Gl[tr][s] = f2b((s <= tr) ? gacc[nf][i] : 0.f);
      }
    }
  }
  __syncthreads();
  // wave w: rows w*16..+16, all 64 d (4 n-frags)
  f32x4 acc[4] = {};
  // phase 1: K=64 (s): A = Gl rows, B = ut rows (global)
#pragma unroll
  for (int kk = 0; kk < 2; ++kk) {
    short8 a = *(const short8*)&Gl[w * 16 + (l & 15)][kk * 32 + (l >> 4) * 8];
#pragma unroll
    for (int n = 0; n < 4; ++n) {
      int d = d0 + n * 16 + (l & 15);
      short8 bb = *(const short8*)&ut[((size_t)bc * DI + d) * CL + kk * 32 + (l >> 4) * 8];
      acc[n] = __builtin_amdgcn_mfma_f32_16x16x32_bf16(a, bb, acc[n], 0, 0, 0);
    }
  }
  // phase 2: K=128 (n-state): A = Cl rows, B = hstb rows (global)
#pragma unroll
  for (int kk = 0; kk < 4; ++kk) {
    short8 a = *(const short8*)&Cl[w * 16 + (l & 15)][kk * 32 + (l >> 4) * 8];
#pragma unroll
    for (int n = 0; n < 4; ++n) {
      int d = d0 + n * 16 + (l & 15);
      short8 bb = *(const short8*)&hstb[((size_t)(b * DI + d)) * (NC * 128) + c * 128 + kk * 32 + (l >> 4) * 8];
      acc[n] = __builtin_amdgcn_mfma_f32_16x16x32_bf16(a, bb, acc[n], 0, 0, 0);
    }
  }
#pragma unroll
  for (int n = 0; n < 4; ++n) {
    int d = d0 + n * 16 + (l & 15);
#pragma unroll
    for (int i = 0; i < 4; ++i) {
      int gr = brow + w * 16 + (l >> 4) * 4 + i;
      float Dv = D[(size_t)gr * DI + d];
      float res = b2f(xr_bf[(size_t)gr * 2048 + 1024 + d]);
      yr[(size_t)gr * DI + d] = f2b(acc[n][i] * Dv + res);
    }
  }
}

extern "C" void kernel_launch(void* const* d_in, const int* in_sizes, int n_in,
                              void* d_out, int out_size, void* d_ws, size_t ws_size,
                              hipStream_t stream) {
  const float* x      = (const float*)d_in[0];
  const float* W_in   = (const float*)d_in[1];
  const float* conv_w = (const float*)d_in[2];
  const float* conv_b = (const float*)d_in[3];
  const float* W_x    = (const float*)d_in[4];
  const float* W_dt   = (const float*)d_in[5];
  const float* b_dt   = (const float*)d_in[6];
  const float* W_out  = (const float*)d_in[7];
  float* out = (float*)d_out;
  float* ws = (float*)d_ws;

  // workspace (float units), all disjoint; total 13,631,488 floats = 54.5 MB
  ushortT* xr_bf = (ushortT*)ws;                  // [2048,2048] bf16
  ushortT* u_bf  = (ushortT*)(ws + 2097152);      // [2048,1024] bf16
  float*   dbl   = ws + 3145728;                  // [2048,288] fp32
  float*   Dc    = ws + 3735552;                  // [2048,1024] fp32
  ushortT* ut    = (ushortT*)(ws + 5832704);      // [32,1024,64] bf16
  ushortT* zb    = (ushortT*)(ws + 6881280);      // [2048,16,128] bf16
  ushortT* hstb  = (ushortT*)(ws + 8978432);      // [2048,16,128] bf16
  ushortT* x_bf  = (ushortT*)(ws + 11075584);     // [2048,512] bf16
  ushortT* Wt_in = (ushortT*)(ws + 11599872);     // [2048,512] bf16
  ushortT* Wt_x  = (ushortT*)(ws + 12124160);     // [384,1024] bf16
  ushortT* Wt_out= (ushortT*)(ws + 12320768);     // [512,1024] bf16
  ushortT* yr_bf = (ushortT*)(ws + 12582912);     // [2048,1024] bf16

  dim3 blk(256);
  // 1) weight transposes + x cvt
  prep_all<<<2944, dim3(32, 8), 0, stream>>>(W_in, W_x, W_out, x,
                                             Wt_in, Wt_x, Wt_out, x_bf);
  // 2) in-proj: xr = x @ W_in (bf16)  M=2048 N=2048 K=512; grid 16x16 flat
  gemm_mfma<1><<<256, blk, 0, stream>>>(x_bf, Wt_in, xr_bf, 2 * DI, DM, 2 * DI, 16);
  // 3) conv -> u (bf16)
  conv_kernel<<<2048, blk, 0, stream>>>(xr_bf, conv_w, conv_b, u_bf);
  // 4) x-proj: dbl = u @ W_x (fp32)  M=2048 N=288 K=1024; 64-tile grid 5x32=160
  gemm64<0><<<160, blk, 0, stream>>>(u_bf, Wt_x, dbl, DTR + 2 * DS, DI, DTR + 2 * DS, 5);
  // 5) megachunk: dt-proj + decay + ut + Z  (512 blocks, 2/CU)
  megachunk<<<dim3(16, 32), blk, 0, stream>>>(dbl, W_dt, b_dt, u_bf, Dc, ut, zb);
  // 6) chunk-boundary combine -> hstb (entry states, bf16)
  scan_pass2<<<512, blk, 0, stream>>>(zb, Dc, hstb);
  // 7) Y = D*(G@ut + C@h_entry) + res -> yr_bf  (512 blocks)
  gemm_y<<<dim3(16, 32), blk, 0, stream>>>(dbl, ut, hstb, Dc, xr_bf, yr_bf);
  // 8) out-proj: out = yr @ W_out (fp32)  M=2048 N=512 K=1024; 64-tile 8x32=256
  gemm64<0><<<256, blk, 0, stream>>>(yr_bf, Wt_out, out, DM, DI, DM, 8);
}

// Round 12
// 98.175 us; speedup vs baseline: 1.8536x; 1.0362x over previous
//
#include <hip/hip_runtime.h>
#include <math.h>

#define S_LEN 1024
#define BATCH 2
#define DM 512
#define DI 1024
#define DS 128
#define DTR 32
#define CL 64            // chunk length
#define NC (S_LEN / CL)  // 16 chunks

typedef unsigned short ushortT;
typedef __attribute__((ext_vector_type(8))) short short8;
typedef __attribute__((ext_vector_type(4))) float f32x4;

__device__ __forceinline__ ushortT f2b(float f) {
  unsigned u = __builtin_bit_cast(unsigned, f);
  unsigned r = (u + 0x7fff + ((u >> 16) & 1)) >> 16;  // RNE
  return (ushortT)r;
}
__device__ __forceinline__ float b2f(ushortT h) {
  return __builtin_bit_cast(float, (unsigned)h << 16);
}

#define GLOAD16(g, l)                                                     \
  __builtin_amdgcn_global_load_lds(                                       \
      (const __attribute__((address_space(1))) void*)(g),                 \
      (__attribute__((address_space(3))) void*)(l), 16, 0, 0)

// ---- gemm64: 64x64 tile, 4 waves (2x2, each 32x32), XCD-swizzled flat grid.
// High blocks/CU -> latency-tolerant for all three projection GEMMs.
// MODE 0: fp32 out; 1: bf16 out.
template<int MODE>
__global__ __launch_bounds__(256) void gemm64(
    const ushortT* __restrict__ A, const ushortT* __restrict__ Bt,
    void* __restrict__ Cout, int N, int K, int ldc, int nbx) {
  __shared__ ushortT As[64 * 32];
  __shared__ ushortT Bs[64 * 32];
  const int nwg = gridDim.x;
  const int bid = blockIdx.x;
  const int flat = (bid & 7) * (nwg >> 3) + (bid >> 3);
  const int bxi = flat % nbx, byi = flat / nbx;
  const int bm = byi * 64, bn = bxi * 64;
  const int tid = threadIdx.x;
  const int l = tid & 63, w = tid >> 6;
  const int wr = w >> 1, wc = w & 1;
  const int srow = tid >> 2, scol = (tid & 3) * 8;  // 256 thr: 64 rows x 32 cols
  f32x4 acc[2][2] = {};
  for (int k0 = 0; k0 < K; k0 += 32) {
    GLOAD16(A + (size_t)(bm + srow) * K + k0 + scol, &As[(size_t)tid * 8]);
    GLOAD16(Bt + (size_t)(bn + srow) * K + k0 + scol, &Bs[(size_t)tid * 8]);
    __syncthreads();
    short8 a[2], b[2];
#pragma unroll
    for (int m = 0; m < 2; ++m)
      a[m] = *(const short8*)&As[(wr * 32 + m * 16 + (l & 15)) * 32 + (l >> 4) * 8];
#pragma unroll
    for (int n = 0; n < 2; ++n)
      b[n] = *(const short8*)&Bs[(wc * 32 + n * 16 + (l & 15)) * 32 + (l >> 4) * 8];
#pragma unroll
    for (int m = 0; m < 2; ++m)
#pragma unroll
      for (int n = 0; n < 2; ++n)
        acc[m][n] = __builtin_amdgcn_mfma_f32_16x16x32_bf16(a[m], b[n], acc[m][n], 0, 0, 0);
    __syncthreads();
  }
#pragma unroll
  for (int m = 0; m < 2; ++m) {
    int grow = bm + wr * 32 + m * 16 + (l >> 4) * 4;
#pragma unroll
    for (int n = 0; n < 2; ++n) {
      int gcol = bn + wc * 32 + n * 16 + (l & 15);
      if (gcol >= N) continue;
#pragma unroll
      for (int i = 0; i < 4; ++i) {
        float v = acc[m][n][i];
        if (MODE == 1)
          ((ushortT*)Cout)[(size_t)(grow + i) * ldc + gcol] = f2b(v);
        else
          ((float*)Cout)[(size_t)(grow + i) * ldc + gcol] = v;
      }
    }
  }
}

// ---- prep_all: weight transposes (fp32->bf16, [K,N]->[Npad,K], ushort2
// stores) + x cvt. blocks [0,1024) W_in; [1024,1408) W_x(pad 384);
// [1408,1920) W_out; [1920,2944) x -> x_bf.
__global__ __launch_bounds__(256) void prep_all(
    const float* __restrict__ W_in, const float* __restrict__ W_x,
    const float* __restrict__ W_out, const float* __restrict__ x,
    ushortT* __restrict__ Wt_in, ushortT* __restrict__ Wt_x,
    ushortT* __restrict__ Wt_out, ushortT* __restrict__ x_bf) {
  __shared__ float tb[32][33];
  int bid = blockIdx.x;
  int tx = threadIdx.x, ty = threadIdx.y;  // (32,8)
  const float* in; ushortT* out; int K, N, bx, by;
  if (bid < 1024)      { in = W_in;  out = Wt_in;  K = 512;  N = 2048; bx = bid & 63; by = bid >> 6; }
  else if (bid < 1408) { int t2 = bid - 1024; in = W_x;   out = Wt_x;   K = 1024; N = 288;  bx = t2 % 12; by = t2 / 12; }
  else if (bid < 1920) { int t2 = bid - 1408; in = W_out; out = Wt_out; K = 1024; N = 512;  bx = t2 % 16; by = t2 / 16; }
  else {
    int i = (bid - 1920) * 256 + ty * 32 + tx;
    float4 v = ((const float4*)x)[i];
    ushort4 o; o.x = f2b(v.x); o.y = f2b(v.y); o.z = f2b(v.z); o.w = f2b(v.w);
    ((ushort4*)x_bf)[i] = o;
    return;
  }
  int n0 = bx * 32, k0 = by * 32;
  int flat = ty * 32 + tx;
  if (n0 < N) {
#pragma unroll
    for (int i = 0; i < 4; ++i)
      tb[ty + 8 * i][tx] = in[(size_t)(k0 + ty + 8 * i) * N + n0 + tx];
    __syncthreads();
#pragma unroll
    for (int j = 0; j < 2; ++j) {
      int idx = j * 256 + flat;        // 0..511
      int r = idx >> 4, c2 = idx & 15; // 32 rows x 16 ushort2 cols
      ushort2 o;
      o.x = f2b(tb[2 * c2][r]);
      o.y = f2b(tb[2 * c2 + 1][r]);
      *(ushort2*)&out[(size_t)(n0 + r) * K + k0 + 2 * c2] = o;
    }
  } else {
    ushort2 z; z.x = 0; z.y = 0;
#pragma unroll
    for (int j = 0; j < 2; ++j) {
      int idx = j * 256 + flat;
      int r = idx >> 4, c2 = idx & 15;
      *(ushort2*)&out[(size_t)(n0 + r) * K + k0 + 2 * c2] = z;
    }
  }
}

// ---- depthwise causal conv, 4 d per thread (ushort4) ------------------------
__global__ __launch_bounds__(256) void conv_kernel(
    const ushortT* __restrict__ xr, const float* __restrict__ w,
    const float* __restrict__ b, ushortT* __restrict__ u) {
  int idx = blockIdx.x * blockDim.x + threadIdx.x;
  int g = idx & 255;
  int s = (idx >> 8) & (S_LEN - 1);
  int bb = idx >> 18;
  int d = g * 4;
  float4 bias = *(const float4*)&b[d];
  float4 w0 = *(const float4*)&w[(d + 0) * 4];
  float4 w1 = *(const float4*)&w[(d + 1) * 4];
  float4 w2 = *(const float4*)&w[(d + 2) * 4];
  float4 w3 = *(const float4*)&w[(d + 3) * 4];
  float a0 = bias.x, a1 = bias.y, a2 = bias.z, a3 = bias.w;
  const ushortT* xs = xr + (size_t)(bb * S_LEN) * (2 * DI) + d;
#pragma unroll
  for (int k = 0; k < 4; ++k) {
    int si = s - 3 + k;
    if (si >= 0) {
      ushort4 v = *(const ushort4*)&xs[(size_t)si * (2 * DI)];
      float wk0 = ((const float*)&w0)[k], wk1 = ((const float*)&w1)[k];
      float wk2 = ((const float*)&w2)[k], wk3 = ((const float*)&w3)[k];
      a0 = fmaf(b2f(v.x), wk0, a0);
      a1 = fmaf(b2f(v.y), wk1, a1);
      a2 = fmaf(b2f(v.z), wk2, a2);
      a3 = fmaf(b2f(v.w), wk3, a3);
    }
  }
  ushort4 o; o.x = f2b(a0); o.y = f2b(a1); o.z = f2b(a2); o.w = f2b(a3);
  *(ushort4*)&u[(size_t)idx * 4] = o;
}

// ---- megachunk: per (dg, bc) 64-d slice: dt-proj + softplus/clip + cumprod
//      + ut + Z = ut @ B^T. 58 KB LDS -> 2 blocks/CU. Z-MFMA issues before
//      the D/ut global writes so store latency drains under the matrix work.
__global__ __launch_bounds__(256) void megachunk(
    const float* __restrict__ dbl, const float* __restrict__ W_dt,
    const float* __restrict__ b_dt, const ushortT* __restrict__ u_bf,
    float* __restrict__ D, ushortT* __restrict__ ut,
    ushortT* __restrict__ zb) {
  __shared__ ushortT Btl[128][72];   // B^T[n][s]
  __shared__ float   Dl[64][66];     // om -> cumprod D, [d][s]
  __shared__ ushortT utl[64][72];    // ut[d][s]
  __shared__ float   dtl[64][36];    // dbl[:,0:32]
  __shared__ ushortT Wl[32][68];     // W_dt slice bf16 [k][d]
  const int t = threadIdx.x;
  const int dg = blockIdx.x, bc = blockIdx.y;
  const int b = bc >> 4, c = bc & 15;
  const size_t rowbase = (size_t)(b * S_LEN + c * CL) * DI + dg * 64;

#pragma unroll
  for (int j = 0; j < 8; ++j) {
    int idx4 = j * 256 + t;
    int s = idx4 >> 5, n4 = (idx4 & 31) * 4;
    float4 v = *(const float4*)&dbl[(size_t)(bc * 64 + s) * 288 + 32 + n4];
    Btl[n4][s] = f2b(v.x); Btl[n4 + 1][s] = f2b(v.y);
    Btl[n4 + 2][s] = f2b(v.z); Btl[n4 + 3][s] = f2b(v.w);
  }
#pragma unroll
  for (int j = 0; j < 2; ++j) {
    int idx4 = j * 256 + t;
    int s = idx4 >> 3, k4 = (idx4 & 7) * 4;
    *(float4*)&dtl[s][k4] = *(const float4*)&dbl[(size_t)(bc * 64 + s) * 288 + k4];
  }
#pragma unroll
  for (int j = 0; j < 4; ++j) {
    int idx2 = j * 256 + t;
    int k = idx2 >> 5, d2 = (idx2 & 31) * 2;
    float2 v = *(const float2*)&W_dt[(size_t)k * DI + dg * 64 + d2];
    Wl[k][d2] = f2b(v.x); Wl[k][d2 + 1] = f2b(v.y);
  }
  __syncthreads();

  // dt-proj: lane = d, wave = s-quarter; W hoisted to registers
  {
    int d = t & 63, sq = t >> 6;
    float wreg[32];
#pragma unroll
    for (int k = 0; k < 32; ++k) wreg[k] = b2f(Wl[k][d]);
    float bias = b_dt[dg * 64 + d] + 1e-4f;
#pragma unroll 4
    for (int j = 0; j < 16; ++j) {
      int s = sq * 16 + j;
      float acc = bias;
#pragma unroll
      for (int k = 0; k < 32; ++k) acc = fmaf(dtl[s][k], wreg[k], acc);
      acc = (acc > 20.f) ? acc : log1pf(expf(acc));
      acc = fminf(fmaxf(acc, 0.001f), 0.1f);
      Dl[d][s] = 1.f - acc;
    }
  }
  __syncthreads();

  if (t < 64) {
    float cum = 1.f;
#pragma unroll 16
    for (int s = 0; s < CL; ++s) { cum *= Dl[t][s]; Dl[t][s] = cum; }
  }
  __syncthreads();

  // ut build: u float4 (8 bf16) / Dl -> utl[d][s]
#pragma unroll
  for (int j = 0; j < 2; ++j) {
    int idx8 = j * 256 + t;
    int s = idx8 >> 3, d8 = (idx8 & 7) * 8;
    float4 raw = *(const float4*)&u_bf[rowbase + (size_t)s * DI + d8];
    const ushortT* up = (const ushortT*)&raw;
#pragma unroll
    for (int k = 0; k < 8; ++k)
      utl[d8 + k][s] = f2b(b2f(up[k]) / Dl[d8 + k][s]);
  }
  __syncthreads();

  // Z = utl @ Btl^T first (MFMA), global writes after
  {
    const int l = t & 63, w = t >> 6;
    f32x4 acc[8] = {};
#pragma unroll
    for (int kk = 0; kk < 2; ++kk) {
      short8 a = *(const short8*)&utl[w * 16 + (l & 15)][kk * 32 + (l >> 4) * 8];
#pragma unroll
      for (int n = 0; n < 8; ++n) {
        short8 bb = *(const short8*)&Btl[n * 16 + (l & 15)][kk * 32 + (l >> 4) * 8];
        acc[n] = __builtin_amdgcn_mfma_f32_16x16x32_bf16(a, bb, acc[n], 0, 0, 0);
      }
    }
#pragma unroll
    for (int n = 0; n < 8; ++n) {
      int gn = n * 16 + (l & 15);
#pragma unroll
      for (int i = 0; i < 4; ++i) {
        int d = dg * 64 + w * 16 + (l >> 4) * 4 + i;
        zb[(((size_t)(b * DI + d)) * NC + c) * 128 + gn] = f2b(acc[n][i]);
      }
    }
  }

  // D global write [s][d] float4
#pragma unroll
  for (int j = 0; j < 4; ++j) {
    int idx4 = j * 256 + t;
    int s = idx4 >> 4, d4 = (idx4 & 15) * 4;
    float4 v;
    v.x = Dl[d4][s]; v.y = Dl[d4 + 1][s]; v.z = Dl[d4 + 2][s]; v.w = Dl[d4 + 3][s];
    *(float4*)&D[rowbase + (size_t)s * DI + d4] = v;
  }
  // ut global write (rows d)
#pragma unroll
  for (int j = 0; j < 2; ++j) {
    int idx8 = j * 256 + t;
    int d = idx8 >> 3, s8 = (idx8 & 7) * 8;
    float4 v; ushortT* vp = (ushortT*)&v;
#pragma unroll
    for (int k = 0; k < 8; ++k) vp[k] = utl[d][s8 + k];
    *(float4*)&ut[((size_t)bc * DI + dg * 64 + d) * CL + s8] = v;
  }
}

// ---- pass2: h_entry chain over chunks; unrolled so loads hoist --------------
__global__ __launch_bounds__(256) void scan_pass2(
    const ushortT* __restrict__ zb, const float* __restrict__ D,
    ushortT* __restrict__ hstb) {
  int wid = (blockIdx.x * blockDim.x + threadIdx.x) >> 6;  // 0..2047 = b*DI+d
  int lane = threadIdx.x & 63;
  int b = wid >> 10, d = wid & (DI - 1);
  size_t base = (size_t)wid * NC * 128;
  float h0 = 0.f, h1 = 0.f;
#pragma unroll
  for (int c = 0; c < NC; ++c) {
    float dend = D[((size_t)(b * S_LEN + c * CL + CL - 1)) * DI + d];
    ushort2 z2 = *(const ushort2*)&zb[base + c * 128 + 2 * lane];
    ushort2 he;
    he.x = f2b(h0); he.y = f2b(h1);
    *(ushort2*)&hstb[base + c * 128 + 2 * lane] = he;
    h0 = dend * (h0 + b2f(z2.x));
    h1 = dend * (h1 + b2f(z2.y));
  }
}

// ---- Y (64-d blocks): stage B,C; G = tril(C.B^T);
//      yr[t,d] = bf16( D[t,d]*( G@ut + C@hstb ) + res ) ----------------------
__global__ __launch_bounds__(256) void gemm_y(
    const float* __restrict__ dbl, const ushortT* __restrict__ ut,
    const ushortT* __restrict__ hstb, const float* __restrict__ D,
    const ushortT* __restrict__ xr_bf, ushortT* __restrict__ yr) {
  __shared__ ushortT Bl[64][136];
  __shared__ ushortT Cl[64][136];
  __shared__ ushortT Gl[64][72];
  const int tid = threadIdx.x;
  const int l = tid & 63, w = tid >> 6;
  const int bc = blockIdx.y, d0 = blockIdx.x * 64;
  const int b = bc >> 4, c = bc & 15;
  const int brow = b * S_LEN + c * CL;
#pragma unroll
  for (int j = 0; j < 16; ++j) {
    int idx4 = j * 256 + tid;
    int row = idx4 >> 6, c4 = (idx4 & 63) * 4;
    float4 v = *(const float4*)&dbl[(size_t)(bc * 64 + row) * 288 + 32 + c4];
    ushortT o0 = f2b(v.x), o1 = f2b(v.y), o2 = f2b(v.z), o3 = f2b(v.w);
    if (c4 < 128) { Bl[row][c4] = o0; Bl[row][c4+1] = o1; Bl[row][c4+2] = o2; Bl[row][c4+3] = o3; }
    else { int cc = c4 - 128; Cl[row][cc] = o0; Cl[row][cc+1] = o1; Cl[row][cc+2] = o2; Cl[row][cc+3] = o3; }
  }
  __syncthreads();
  {
    f32x4 gacc[4] = {};
#pragma unroll
    for (int kk = 0; kk < 4; ++kk) {
      short8 a = *(const short8*)&Cl[w * 16 + (l & 15)][kk * 32 + (l >> 4) * 8];
#pragma unroll
      for (int nf = 0; nf < 4; ++nf) {
        short8 bb = *(const short8*)&Bl[nf * 16 + (l & 15)][kk * 32 + (l >> 4) * 8];
        gacc[nf] = __builtin_amdgcn_mfma_f32_16x16x32_bf16(a, bb, gacc[nf], 0, 0, 0);
      }
    }
#pragma unroll
    for (int nf = 0; nf < 4; ++nf) {
      int s = nf * 16 + (l & 15);
#pragma unroll
      for (int i = 0; i < 4; ++i) {
        int tr = w * 16 + (l >> 4) * 4 + i;
        Gl[tr][s] = f2b((s <= tr) ? gacc[nf][i] : 0.f);
      }
    }
  }
  __syncthreads();
  f32x4 acc[4] = {};
#pragma unroll
  for (int kk = 0; kk < 2; ++kk) {
    short8 a = *(const short8*)&Gl[w * 16 + (l & 15)][kk * 32 + (l >> 4) * 8];
#pragma unroll
    for (int n = 0; n < 4; ++n) {
      int d = d0 + n * 16 + (l & 15);
      short8 bb = *(const short8*)&ut[((size_t)bc * DI + d) * CL + kk * 32 + (l >> 4) * 8];
      acc[n] = __builtin_amdgcn_mfma_f32_16x16x32_bf16(a, bb, acc[n], 0, 0, 0);
    }
  }
#pragma unroll
  for (int kk = 0; kk < 4; ++kk) {
    short8 a = *(const short8*)&Cl[w * 16 + (l & 15)][kk * 32 + (l >> 4) * 8];
#pragma unroll
    for (int n = 0; n < 4; ++n) {
      int d = d0 + n * 16 + (l & 15);
      short8 bb = *(const short8*)&hstb[((size_t)(b * DI + d)) * (NC * 128) + c * 128 + kk * 32 + (l >> 4) * 8];
      acc[n] = __builtin_amdgcn_mfma_f32_16x16x32_bf16(a, bb, acc[n], 0, 0, 0);
    }
  }
#pragma unroll
  for (int n = 0; n < 4; ++n) {
    int d = d0 + n * 16 + (l & 15);
#pragma unroll
    for (int i = 0; i < 4; ++i) {
      int gr = brow + w * 16 + (l >> 4) * 4 + i;
      float Dv = D[(size_t)gr * DI + d];
      float res = b2f(xr_bf[(size_t)gr * 2048 + 1024 + d]);
      yr[(size_t)gr * DI + d] = f2b(acc[n][i] * Dv + res);
    }
  }
}

extern "C" void kernel_launch(void* const* d_in, const int* in_sizes, int n_in,
                              void* d_out, int out_size, void* d_ws, size_t ws_size,
                              hipStream_t stream) {
  const float* x      = (const float*)d_in[0];
  const float* W_in   = (const float*)d_in[1];
  const float* conv_w = (const float*)d_in[2];
  const float* conv_b = (const float*)d_in[3];
  const float* W_x    = (const float*)d_in[4];
  const float* W_dt   = (const float*)d_in[5];
  const float* b_dt   = (const float*)d_in[6];
  const float* W_out  = (const float*)d_in[7];
  float* out = (float*)d_out;
  float* ws = (float*)d_ws;

  // workspace (float units), all disjoint; total 13,631,488 floats = 54.5 MB
  ushortT* xr_bf = (ushortT*)ws;                  // [2048,2048] bf16
  ushortT* u_bf  = (ushortT*)(ws + 2097152);      // [2048,1024] bf16
  float*   dbl   = ws + 3145728;                  // [2048,288] fp32
  float*   Dc    = ws + 3735552;                  // [2048,1024] fp32
  ushortT* ut    = (ushortT*)(ws + 5832704);      // [32,1024,64] bf16
  ushortT* zb    = (ushortT*)(ws + 6881280);      // [2048,16,128] bf16
  ushortT* hstb  = (ushortT*)(ws + 8978432);      // [2048,16,128] bf16
  ushortT* x_bf  = (ushortT*)(ws + 11075584);     // [2048,512] bf16
  ushortT* Wt_in = (ushortT*)(ws + 11599872);     // [2048,512] bf16
  ushortT* Wt_x  = (ushortT*)(ws + 12124160);     // [384,1024] bf16
  ushortT* Wt_out= (ushortT*)(ws + 12320768);     // [512,1024] bf16
  ushortT* yr_bf = (ushortT*)(ws + 12582912);     // [2048,1024] bf16

  dim3 blk(256);
  // 1) weight transposes + x cvt
  prep_all<<<2944, dim3(32, 8), 0, stream>>>(W_in, W_x, W_out, x,
                                             Wt_in, Wt_x, Wt_out, x_bf);
  // 2) in-proj: xr = x @ W_in (bf16)  M=2048 N=2048 K=512; 64-tile 32x32=1024
  gemm64<1><<<1024, blk, 0, stream>>>(x_bf, Wt_in, xr_bf, 2 * DI, DM, 2 * DI, 32);
  // 3) conv -> u (bf16)
  conv_kernel<<<2048, blk, 0, stream>>>(xr_bf, conv_w, conv_b, u_bf);
  // 4) x-proj: dbl = u @ W_x (fp32)  M=2048 N=288 K=1024; 64-tile 5x32=160
  gemm64<0><<<160, blk, 0, stream>>>(u_bf, Wt_x, dbl, DTR + 2 * DS, DI, DTR + 2 * DS, 5);
  // 5) megachunk: dt-proj + decay + ut + Z  (512 blocks, 2/CU)
  megachunk<<<dim3(16, 32), blk, 0, stream>>>(dbl, W_dt, b_dt, u_bf, Dc, ut, zb);
  // 6) chunk-boundary combine -> hstb (entry states, bf16)
  scan_pass2<<<512, blk, 0, stream>>>(zb, Dc, hstb);
  // 7) Y = D*(G@ut + C@h_entry) + res -> yr_bf  (512 blocks)
  gemm_y<<<dim3(16, 32), blk, 0, stream>>>(dbl, ut, hstb, Dc, xr_bf, yr_bf);
  // 8) out-proj: out = yr @ W_out (fp32)  M=2048 N=512 K=1024; 64-tile 8x32=256
  gemm64<0><<<256, blk, 0, stream>>>(yr_bf, Wt_out, out, DM, DI, DM, 8);
}

// Round 13
// 96.922 us; speedup vs baseline: 1.8776x; 1.0129x over previous
//
#include <hip/hip_runtime.h>
#include <math.h>

#define S_LEN 1024
#define BATCH 2
#define DM 512
#define DI 1024
#define DS 128
#define DTR 32
#define CL 64            // chunk length
#define NC (S_LEN / CL)  // 16 chunks

typedef unsigned short ushortT;
typedef __attribute__((ext_vector_type(8))) short short8;
typedef __attribute__((ext_vector_type(4))) float f32x4;

__device__ __forceinline__ ushortT f2b(float f) {
  unsigned u = __builtin_bit_cast(unsigned, f);
  unsigned r = (u + 0x7fff + ((u >> 16) & 1)) >> 16;  // RNE
  return (ushortT)r;
}
__device__ __forceinline__ float b2f(ushortT h) {
  return __builtin_bit_cast(float, (unsigned)h << 16);
}

#define GLOAD16(g, l)                                                     \
  __builtin_amdgcn_global_load_lds(                                       \
      (const __attribute__((address_space(1))) void*)(g),                 \
      (__attribute__((address_space(3))) void*)(l), 16, 0, 0)

// ---- gemm64: 64x64 tile, 4 waves (2x2, each 32x32), XCD-swizzled flat grid,
// double-buffered LDS (T3-min 2-phase: stage next tile BEFORE computing
// current; single barrier per iter -> load latency drains under MFMA).
// MODE 0: fp32 out; 1: bf16 out.
template<int MODE>
__global__ __launch_bounds__(256) void gemm64(
    const ushortT* __restrict__ A, const ushortT* __restrict__ Bt,
    void* __restrict__ Cout, int N, int K, int ldc, int nbx) {
  __shared__ ushortT As[2][64 * 32];
  __shared__ ushortT Bs[2][64 * 32];
  const int nwg = gridDim.x;
  const int bid = blockIdx.x;
  const int flat = (bid & 7) * (nwg >> 3) + (bid >> 3);
  const int bxi = flat % nbx, byi = flat / nbx;
  const int bm = byi * 64, bn = bxi * 64;
  const int tid = threadIdx.x;
  const int l = tid & 63, w = tid >> 6;
  const int wr = w >> 1, wc = w & 1;
  const int srow = tid >> 2, scol = (tid & 3) * 8;  // 256 thr: 64 rows x 32 cols
  const ushortT* gA = A + (size_t)(bm + srow) * K + scol;
  const ushortT* gB = Bt + (size_t)(bn + srow) * K + scol;
  f32x4 acc[2][2] = {};
  const int nt = K >> 5;
  // prologue: stage tile 0
  GLOAD16(gA, &As[0][(size_t)tid * 8]);
  GLOAD16(gB, &Bs[0][(size_t)tid * 8]);
  __syncthreads();
  int cur = 0;
  for (int t = 0; t < nt; ++t) {
    if (t + 1 < nt) {  // stage next tile into other buffer (overlaps MFMA)
      GLOAD16(gA + (t + 1) * 32, &As[cur ^ 1][(size_t)tid * 8]);
      GLOAD16(gB + (t + 1) * 32, &Bs[cur ^ 1][(size_t)tid * 8]);
    }
    short8 a[2], b[2];
#pragma unroll
    for (int m = 0; m < 2; ++m)
      a[m] = *(const short8*)&As[cur][(wr * 32 + m * 16 + (l & 15)) * 32 + (l >> 4) * 8];
#pragma unroll
    for (int n = 0; n < 2; ++n)
      b[n] = *(const short8*)&Bs[cur][(wc * 32 + n * 16 + (l & 15)) * 32 + (l >> 4) * 8];
#pragma unroll
    for (int m = 0; m < 2; ++m)
#pragma unroll
      for (int n = 0; n < 2; ++n)
        acc[m][n] = __builtin_amdgcn_mfma_f32_16x16x32_bf16(a[m], b[n], acc[m][n], 0, 0, 0);
    __syncthreads();  // drains next-tile loads (ran under MFMA) + read fence
    cur ^= 1;
  }
#pragma unroll
  for (int m = 0; m < 2; ++m) {
    int grow = bm + wr * 32 + m * 16 + (l >> 4) * 4;
#pragma unroll
    for (int n = 0; n < 2; ++n) {
      int gcol = bn + wc * 32 + n * 16 + (l & 15);
      if (gcol >= N) continue;
#pragma unroll
      for (int i = 0; i < 4; ++i) {
        float v = acc[m][n][i];
        if (MODE == 1)
          ((ushortT*)Cout)[(size_t)(grow + i) * ldc + gcol] = f2b(v);
        else
          ((float*)Cout)[(size_t)(grow + i) * ldc + gcol] = v;
      }
    }
  }
}

// ---- prep_all: weight transposes (fp32->bf16, [K,N]->[Npad,K], ushort2
// stores) + x cvt.
__global__ __launch_bounds__(256) void prep_all(
    const float* __restrict__ W_in, const float* __restrict__ W_x,
    const float* __restrict__ W_out, const float* __restrict__ x,
    ushortT* __restrict__ Wt_in, ushortT* __restrict__ Wt_x,
    ushortT* __restrict__ Wt_out, ushortT* __restrict__ x_bf) {
  __shared__ float tb[32][33];
  int bid = blockIdx.x;
  int tx = threadIdx.x, ty = threadIdx.y;  // (32,8)
  const float* in; ushortT* out; int K, N, bx, by;
  if (bid < 1024)      { in = W_in;  out = Wt_in;  K = 512;  N = 2048; bx = bid & 63; by = bid >> 6; }
  else if (bid < 1408) { int t2 = bid - 1024; in = W_x;   out = Wt_x;   K = 1024; N = 288;  bx = t2 % 12; by = t2 / 12; }
  else if (bid < 1920) { int t2 = bid - 1408; in = W_out; out = Wt_out; K = 1024; N = 512;  bx = t2 % 16; by = t2 / 16; }
  else {
    int i = (bid - 1920) * 256 + ty * 32 + tx;
    float4 v = ((const float4*)x)[i];
    ushort4 o; o.x = f2b(v.x); o.y = f2b(v.y); o.z = f2b(v.z); o.w = f2b(v.w);
    ((ushort4*)x_bf)[i] = o;
    return;
  }
  int n0 = bx * 32, k0 = by * 32;
  int flat = ty * 32 + tx;
  if (n0 < N) {
#pragma unroll
    for (int i = 0; i < 4; ++i)
      tb[ty + 8 * i][tx] = in[(size_t)(k0 + ty + 8 * i) * N + n0 + tx];
    __syncthreads();
#pragma unroll
    for (int j = 0; j < 2; ++j) {
      int idx = j * 256 + flat;        // 0..511
      int r = idx >> 4, c2 = idx & 15; // 32 rows x 16 ushort2 cols
      ushort2 o;
      o.x = f2b(tb[2 * c2][r]);
      o.y = f2b(tb[2 * c2 + 1][r]);
      *(ushort2*)&out[(size_t)(n0 + r) * K + k0 + 2 * c2] = o;
    }
  } else {
    ushort2 z; z.x = 0; z.y = 0;
#pragma unroll
    for (int j = 0; j < 2; ++j) {
      int idx = j * 256 + flat;
      int r = idx >> 4, c2 = idx & 15;
      *(ushort2*)&out[(size_t)(n0 + r) * K + k0 + 2 * c2] = z;
    }
  }
}

// ---- depthwise causal conv, 4 d per thread (ushort4) ------------------------
__global__ __launch_bounds__(256) void conv_kernel(
    const ushortT* __restrict__ xr, const float* __restrict__ w,
    const float* __restrict__ b, ushortT* __restrict__ u) {
  int idx = blockIdx.x * blockDim.x + threadIdx.x;
  int g = idx & 255;
  int s = (idx >> 8) & (S_LEN - 1);
  int bb = idx >> 18;
  int d = g * 4;
  float4 bias = *(const float4*)&b[d];
  float4 w0 = *(const float4*)&w[(d + 0) * 4];
  float4 w1 = *(const float4*)&w[(d + 1) * 4];
  float4 w2 = *(const float4*)&w[(d + 2) * 4];
  float4 w3 = *(const float4*)&w[(d + 3) * 4];
  float a0 = bias.x, a1 = bias.y, a2 = bias.z, a3 = bias.w;
  const ushortT* xs = xr + (size_t)(bb * S_LEN) * (2 * DI) + d;
#pragma unroll
  for (int k = 0; k < 4; ++k) {
    int si = s - 3 + k;
    if (si >= 0) {
      ushort4 v = *(const ushort4*)&xs[(size_t)si * (2 * DI)];
      float wk0 = ((const float*)&w0)[k], wk1 = ((const float*)&w1)[k];
      float wk2 = ((const float*)&w2)[k], wk3 = ((const float*)&w3)[k];
      a0 = fmaf(b2f(v.x), wk0, a0);
      a1 = fmaf(b2f(v.y), wk1, a1);
      a2 = fmaf(b2f(v.z), wk2, a2);
      a3 = fmaf(b2f(v.w), wk3, a3);
    }
  }
  ushort4 o; o.x = f2b(a0); o.y = f2b(a1); o.z = f2b(a2); o.w = f2b(a3);
  *(ushort4*)&u[(size_t)idx * 4] = o;
}

// ---- megachunk: per (dg, bc) 64-d slice: dt-proj + softplus/clip + cumprod
//      + ut + Z = ut @ B^T. Z-MFMA before global writes. -------------------
__global__ __launch_bounds__(256) void megachunk(
    const float* __restrict__ dbl, const float* __restrict__ W_dt,
    const float* __restrict__ b_dt, const ushortT* __restrict__ u_bf,
    float* __restrict__ D, ushortT* __restrict__ ut,
    ushortT* __restrict__ zb) {
  __shared__ ushortT Btl[128][72];   // B^T[n][s]
  __shared__ float   Dl[64][66];     // om -> cumprod D, [d][s]
  __shared__ ushortT utl[64][72];    // ut[d][s]
  __shared__ float   dtl[64][36];    // dbl[:,0:32]
  __shared__ ushortT Wl[32][68];     // W_dt slice bf16 [k][d]
  const int t = threadIdx.x;
  const int dg = blockIdx.x, bc = blockIdx.y;
  const int b = bc >> 4, c = bc & 15;
  const size_t rowbase = (size_t)(b * S_LEN + c * CL) * DI + dg * 64;

#pragma unroll
  for (int j = 0; j < 8; ++j) {
    int idx4 = j * 256 + t;
    int s = idx4 >> 5, n4 = (idx4 & 31) * 4;
    float4 v = *(const float4*)&dbl[(size_t)(bc * 64 + s) * 288 + 32 + n4];
    Btl[n4][s] = f2b(v.x); Btl[n4 + 1][s] = f2b(v.y);
    Btl[n4 + 2][s] = f2b(v.z); Btl[n4 + 3][s] = f2b(v.w);
  }
#pragma unroll
  for (int j = 0; j < 2; ++j) {
    int idx4 = j * 256 + t;
    int s = idx4 >> 3, k4 = (idx4 & 7) * 4;
    *(float4*)&dtl[s][k4] = *(const float4*)&dbl[(size_t)(bc * 64 + s) * 288 + k4];
  }
#pragma unroll
  for (int j = 0; j < 4; ++j) {
    int idx2 = j * 256 + t;
    int k = idx2 >> 5, d2 = (idx2 & 31) * 2;
    float2 v = *(const float2*)&W_dt[(size_t)k * DI + dg * 64 + d2];
    Wl[k][d2] = f2b(v.x); Wl[k][d2 + 1] = f2b(v.y);
  }
  __syncthreads();

  {
    int d = t & 63, sq = t >> 6;
    float wreg[32];
#pragma unroll
    for (int k = 0; k < 32; ++k) wreg[k] = b2f(Wl[k][d]);
    float bias = b_dt[dg * 64 + d] + 1e-4f;
#pragma unroll 4
    for (int j = 0; j < 16; ++j) {
      int s = sq * 16 + j;
      float acc = bias;
#pragma unroll
      for (int k = 0; k < 32; ++k) acc = fmaf(dtl[s][k], wreg[k], acc);
      acc = (acc > 20.f) ? acc : log1pf(expf(acc));
      acc = fminf(fmaxf(acc, 0.001f), 0.1f);
      Dl[d][s] = 1.f - acc;
    }
  }
  __syncthreads();

  if (t < 64) {
    float cum = 1.f;
#pragma unroll 16
    for (int s = 0; s < CL; ++s) { cum *= Dl[t][s]; Dl[t][s] = cum; }
  }
  __syncthreads();

#pragma unroll
  for (int j = 0; j < 2; ++j) {
    int idx8 = j * 256 + t;
    int s = idx8 >> 3, d8 = (idx8 & 7) * 8;
    float4 raw = *(const float4*)&u_bf[rowbase + (size_t)s * DI + d8];
    const ushortT* up = (const ushortT*)&raw;
#pragma unroll
    for (int k = 0; k < 8; ++k)
      utl[d8 + k][s] = f2b(b2f(up[k]) / Dl[d8 + k][s]);
  }
  __syncthreads();

  // Z = utl @ Btl^T first (MFMA), global writes after
  {
    const int l = t & 63, w = t >> 6;
    f32x4 acc[8] = {};
#pragma unroll
    for (int kk = 0; kk < 2; ++kk) {
      short8 a = *(const short8*)&utl[w * 16 + (l & 15)][kk * 32 + (l >> 4) * 8];
#pragma unroll
      for (int n = 0; n < 8; ++n) {
        short8 bb = *(const short8*)&Btl[n * 16 + (l & 15)][kk * 32 + (l >> 4) * 8];
        acc[n] = __builtin_amdgcn_mfma_f32_16x16x32_bf16(a, bb, acc[n], 0, 0, 0);
      }
    }
#pragma unroll
    for (int n = 0; n < 8; ++n) {
      int gn = n * 16 + (l & 15);
#pragma unroll
      for (int i = 0; i < 4; ++i) {
        int d = dg * 64 + w * 16 + (l >> 4) * 4 + i;
        zb[(((size_t)(b * DI + d)) * NC + c) * 128 + gn] = f2b(acc[n][i]);
      }
    }
  }

#pragma unroll
  for (int j = 0; j < 4; ++j) {
    int idx4 = j * 256 + t;
    int s = idx4 >> 4, d4 = (idx4 & 15) * 4;
    float4 v;
    v.x = Dl[d4][s]; v.y = Dl[d4 + 1][s]; v.z = Dl[d4 + 2][s]; v.w = Dl[d4 + 3][s];
    *(float4*)&D[rowbase + (size_t)s * DI + d4] = v;
  }
#pragma unroll
  for (int j = 0; j < 2; ++j) {
    int idx8 = j * 256 + t;
    int d = idx8 >> 3, s8 = (idx8 & 7) * 8;
    float4 v; ushortT* vp = (ushortT*)&v;
#pragma unroll
    for (int k = 0; k < 8; ++k) vp[k] = utl[d][s8 + k];
    *(float4*)&ut[((size_t)bc * DI + dg * 64 + d) * CL + s8] = v;
  }
}

// ---- pass2: h_entry chain over chunks; unrolled so loads hoist --------------
__global__ __launch_bounds__(256) void scan_pass2(
    const ushortT* __restrict__ zb, const float* __restrict__ D,
    ushortT* __restrict__ hstb) {
  int wid = (blockIdx.x * blockDim.x + threadIdx.x) >> 6;  // 0..2047 = b*DI+d
  int lane = threadIdx.x & 63;
  int b = wid >> 10, d = wid & (DI - 1);
  size_t base = (size_t)wid * NC * 128;
  float h0 = 0.f, h1 = 0.f;
#pragma unroll
  for (int c = 0; c < NC; ++c) {
    float dend = D[((size_t)(b * S_LEN + c * CL + CL - 1)) * DI + d];
    ushort2 z2 = *(const ushort2*)&zb[base + c * 128 + 2 * lane];
    ushort2 he;
    he.x = f2b(h0); he.y = f2b(h1);
    *(ushort2*)&hstb[base + c * 128 + 2 * lane] = he;
    h0 = dend * (h0 + b2f(z2.x));
    h1 = dend * (h1 + b2f(z2.y));
  }
}

// ---- Y (64-d blocks): hoisted ut loads; stage B,C; G = tril(C.B^T);
//      yr[t,d] = bf16( D[t,d]*( G@ut + C@hstb ) + res ) ----------------------
__global__ __launch_bounds__(256) void gemm_y(
    const float* __restrict__ dbl, const ushortT* __restrict__ ut,
    const ushortT* __restrict__ hstb, const float* __restrict__ D,
    const ushortT* __restrict__ xr_bf, ushortT* __restrict__ yr) {
  __shared__ ushortT Bl[64][136];
  __shared__ ushortT Cl[64][136];
  __shared__ ushortT Gl[64][72];
  const int tid = threadIdx.x;
  const int l = tid & 63, w = tid >> 6;
  const int bc = blockIdx.y, d0 = blockIdx.x * 64;
  const int b = bc >> 4, c = bc & 15;
  const int brow = b * S_LEN + c * CL;
  // hoist phase-1 B-operand (ut) global loads: complete under staging + G
  short8 ub[2][4];
#pragma unroll
  for (int kk = 0; kk < 2; ++kk)
#pragma unroll
    for (int n = 0; n < 4; ++n) {
      int d = d0 + n * 16 + (l & 15);
      ub[kk][n] = *(const short8*)&ut[((size_t)bc * DI + d) * CL + kk * 32 + (l >> 4) * 8];
    }
  // stage B|C rows (float4)
#pragma unroll
  for (int j = 0; j < 16; ++j) {
    int idx4 = j * 256 + tid;
    int row = idx4 >> 6, c4 = (idx4 & 63) * 4;
    float4 v = *(const float4*)&dbl[(size_t)(bc * 64 + row) * 288 + 32 + c4];
    ushortT o0 = f2b(v.x), o1 = f2b(v.y), o2 = f2b(v.z), o3 = f2b(v.w);
    if (c4 < 128) { Bl[row][c4] = o0; Bl[row][c4+1] = o1; Bl[row][c4+2] = o2; Bl[row][c4+3] = o3; }
    else { int cc = c4 - 128; Cl[row][cc] = o0; Cl[row][cc+1] = o1; Cl[row][cc+2] = o2; Cl[row][cc+3] = o3; }
  }
  __syncthreads();
  {
    f32x4 gacc[4] = {};
#pragma unroll
    for (int kk = 0; kk < 4; ++kk) {
      short8 a = *(const short8*)&Cl[w * 16 + (l & 15)][kk * 32 + (l >> 4) * 8];
#pragma unroll
      for (int nf = 0; nf < 4; ++nf) {
        short8 bb = *(const short8*)&Bl[nf * 16 + (l & 15)][kk * 32 + (l >> 4) * 8];
        gacc[nf] = __builtin_amdgcn_mfma_f32_16x16x32_bf16(a, bb, gacc[nf], 0, 0, 0);
      }
    }
#pragma unroll
    for (int nf = 0; nf < 4; ++nf) {
      int s = nf * 16 + (l & 15);
#pragma unroll
      for (int i = 0; i < 4; ++i) {
        int tr = w * 16 + (l >> 4) * 4 + i;
        Gl[tr][s] = f2b((s <= tr) ? gacc[nf][i] : 0.f);
      }
    }
  }
  __syncthreads();
  f32x4 acc[4] = {};
  // phase 1: K=64 (s): A = Gl rows, B = hoisted ut frags
#pragma unroll
  for (int kk = 0; kk < 2; ++kk) {
    short8 a = *(const short8*)&Gl[w * 16 + (l & 15)][kk * 32 + (l >> 4) * 8];
#pragma unroll
    for (int n = 0; n < 4; ++n)
      acc[n] = __builtin_amdgcn_mfma_f32_16x16x32_bf16(a, ub[kk][n], acc[n], 0, 0, 0);
  }
  // phase 2: K=128 (n-state): A = Cl rows, B = hstb rows (global)
#pragma unroll
  for (int kk = 0; kk < 4; ++kk) {
    short8 a = *(const short8*)&Cl[w * 16 + (l & 15)][kk * 32 + (l >> 4) * 8];
#pragma unroll
    for (int n = 0; n < 4; ++n) {
      int d = d0 + n * 16 + (l & 15);
      short8 bb = *(const short8*)&hstb[((size_t)(b * DI + d)) * (NC * 128) + c * 128 + kk * 32 + (l >> 4) * 8];
      acc[n] = __builtin_amdgcn_mfma_f32_16x16x32_bf16(a, bb, acc[n], 0, 0, 0);
    }
  }
#pragma unroll
  for (int n = 0; n < 4; ++n) {
    int d = d0 + n * 16 + (l & 15);
#pragma unroll
    for (int i = 0; i < 4; ++i) {
      int gr = brow + w * 16 + (l >> 4) * 4 + i;
      float Dv = D[(size_t)gr * DI + d];
      float res = b2f(xr_bf[(size_t)gr * 2048 + 1024 + d]);
      yr[(size_t)gr * DI + d] = f2b(acc[n][i] * Dv + res);
    }
  }
}

extern "C" void kernel_launch(void* const* d_in, const int* in_sizes, int n_in,
                              void* d_out, int out_size, void* d_ws, size_t ws_size,
                              hipStream_t stream) {
  const float* x      = (const float*)d_in[0];
  const float* W_in   = (const float*)d_in[1];
  const float* conv_w = (const float*)d_in[2];
  const float* conv_b = (const float*)d_in[3];
  const float* W_x    = (const float*)d_in[4];
  const float* W_dt   = (const float*)d_in[5];
  const float* b_dt   = (const float*)d_in[6];
  const float* W_out  = (const float*)d_in[7];
  float* out = (float*)d_out;
  float* ws = (float*)d_ws;

  // workspace (float units), all disjoint; total 13,631,488 floats = 54.5 MB
  ushortT* xr_bf = (ushortT*)ws;                  // [2048,2048] bf16
  ushortT* u_bf  = (ushortT*)(ws + 2097152);      // [2048,1024] bf16
  float*   dbl   = ws + 3145728;                  // [2048,288] fp32
  float*   Dc    = ws + 3735552;                  // [2048,1024] fp32
  ushortT* ut    = (ushortT*)(ws + 5832704);      // [32,1024,64] bf16
  ushortT* zb    = (ushortT*)(ws + 6881280);      // [2048,16,128] bf16
  ushortT* hstb  = (ushortT*)(ws + 8978432);      // [2048,16,128] bf16
  ushortT* x_bf  = (ushortT*)(ws + 11075584);     // [2048,512] bf16
  ushortT* Wt_in = (ushortT*)(ws + 11599872);     // [2048,512] bf16
  ushortT* Wt_x  = (ushortT*)(ws + 12124160);     // [384,1024] bf16
  ushortT* Wt_out= (ushortT*)(ws + 12320768);     // [512,1024] bf16
  ushortT* yr_bf = (ushortT*)(ws + 12582912);     // [2048,1024] bf16

  dim3 blk(256);
  // 1) weight transposes + x cvt
  prep_all<<<2944, dim3(32, 8), 0, stream>>>(W_in, W_x, W_out, x,
                                             Wt_in, Wt_x, Wt_out, x_bf);
  // 2) in-proj: xr = x @ W_in (bf16)  M=2048 N=2048 K=512; 64-tile 32x32=1024
  gemm64<1><<<1024, blk, 0, stream>>>(x_bf, Wt_in, xr_bf, 2 * DI, DM, 2 * DI, 32);
  // 3) conv -> u (bf16)
  conv_kernel<<<2048, blk, 0, stream>>>(xr_bf, conv_w, conv_b, u_bf);
  // 4) x-proj: dbl = u @ W_x (fp32)  M=2048 N=288 K=1024; 64-tile 5x32=160
  gemm64<0><<<160, blk, 0, stream>>>(u_bf, Wt_x, dbl, DTR + 2 * DS, DI, DTR + 2 * DS, 5);
  // 5) megachunk: dt-proj + decay + ut + Z  (512 blocks, 2/CU)
  megachunk<<<dim3(16, 32), blk, 0, stream>>>(dbl, W_dt, b_dt, u_bf, Dc, ut, zb);
  // 6) chunk-boundary combine -> hstb (entry states, bf16)
  scan_pass2<<<512, blk, 0, stream>>>(zb, Dc, hstb);
  // 7) Y = D*(G@ut + C@h_entry) + res -> yr_bf  (512 blocks)
  gemm_y<<<dim3(16, 32), blk, 0, stream>>>(dbl, ut, hstb, Dc, xr_bf, yr_bf);
  // 8) out-proj: out = yr @ W_out (fp32)  M=2048 N=512 K=1024; 64-tile 8x32=256
  gemm64<0><<<256, blk, 0, stream>>>(yr_bf, Wt_out, out, DM, DI, DM, 8);
}

// Round 14
// 94.126 us; speedup vs baseline: 1.9333x; 1.0297x over previous
//
#include <hip/hip_runtime.h>
#include <math.h>

#define S_LEN 1024
#define BATCH 2
#define DM 512
#define DI 1024
#define DS 128
#define DTR 32
#define CL 64            // chunk length
#define NC (S_LEN / CL)  // 16 chunks

typedef unsigned short ushortT;
typedef __attribute__((ext_vector_type(8))) short short8;
typedef __attribute__((ext_vector_type(4))) float f32x4;

__device__ __forceinline__ ushortT f2b(float f) {
  unsigned u = __builtin_bit_cast(unsigned, f);
  unsigned r = (u + 0x7fff + ((u >> 16) & 1)) >> 16;  // RNE
  return (ushortT)r;
}
__device__ __forceinline__ float b2f(ushortT h) {
  return __builtin_bit_cast(float, (unsigned)h << 16);
}

#define GLOAD16(g, l)                                                     \
  __builtin_amdgcn_global_load_lds(                                       \
      (const __attribute__((address_space(1))) void*)(g),                 \
      (__attribute__((address_space(3))) void*)(l), 16, 0, 0)

// ---- gemm64: 64x64 tile, 4 waves (2x2, each 32x32), XCD-swizzled flat grid,
// double-buffered LDS. MODE 0: fp32 out; 1: bf16 out.
template<int MODE>
__global__ __launch_bounds__(256) void gemm64(
    const ushortT* __restrict__ A, const ushortT* __restrict__ Bt,
    void* __restrict__ Cout, int N, int K, int ldc, int nbx) {
  __shared__ ushortT As[2][64 * 32];
  __shared__ ushortT Bs[2][64 * 32];
  const int nwg = gridDim.x;
  const int bid = blockIdx.x;
  const int flat = (bid & 7) * (nwg >> 3) + (bid >> 3);
  const int bxi = flat % nbx, byi = flat / nbx;
  const int bm = byi * 64, bn = bxi * 64;
  const int tid = threadIdx.x;
  const int l = tid & 63, w = tid >> 6;
  const int wr = w >> 1, wc = w & 1;
  const int srow = tid >> 2, scol = (tid & 3) * 8;
  const ushortT* gA = A + (size_t)(bm + srow) * K + scol;
  const ushortT* gB = Bt + (size_t)(bn + srow) * K + scol;
  f32x4 acc[2][2] = {};
  const int nt = K >> 5;
  GLOAD16(gA, &As[0][(size_t)tid * 8]);
  GLOAD16(gB, &Bs[0][(size_t)tid * 8]);
  __syncthreads();
  int cur = 0;
  for (int t = 0; t < nt; ++t) {
    if (t + 1 < nt) {
      GLOAD16(gA + (t + 1) * 32, &As[cur ^ 1][(size_t)tid * 8]);
      GLOAD16(gB + (t + 1) * 32, &Bs[cur ^ 1][(size_t)tid * 8]);
    }
    short8 a[2], b[2];
#pragma unroll
    for (int m = 0; m < 2; ++m)
      a[m] = *(const short8*)&As[cur][(wr * 32 + m * 16 + (l & 15)) * 32 + (l >> 4) * 8];
#pragma unroll
    for (int n = 0; n < 2; ++n)
      b[n] = *(const short8*)&Bs[cur][(wc * 32 + n * 16 + (l & 15)) * 32 + (l >> 4) * 8];
#pragma unroll
    for (int m = 0; m < 2; ++m)
#pragma unroll
      for (int n = 0; n < 2; ++n)
        acc[m][n] = __builtin_amdgcn_mfma_f32_16x16x32_bf16(a[m], b[n], acc[m][n], 0, 0, 0);
    __syncthreads();
    cur ^= 1;
  }
#pragma unroll
  for (int m = 0; m < 2; ++m) {
    int grow = bm + wr * 32 + m * 16 + (l >> 4) * 4;
#pragma unroll
    for (int n = 0; n < 2; ++n) {
      int gcol = bn + wc * 32 + n * 16 + (l & 15);
      if (gcol >= N) continue;
#pragma unroll
      for (int i = 0; i < 4; ++i) {
        float v = acc[m][n][i];
        if (MODE == 1)
          ((ushortT*)Cout)[(size_t)(grow + i) * ldc + gcol] = f2b(v);
        else
          ((float*)Cout)[(size_t)(grow + i) * ldc + gcol] = v;
      }
    }
  }
}

// ---- prep_all: weight transposes (fp32->bf16, [K,N]->[Npad,K], ushort2
// stores) + x cvt.
__global__ __launch_bounds__(256) void prep_all(
    const float* __restrict__ W_in, const float* __restrict__ W_x,
    const float* __restrict__ W_out, const float* __restrict__ x,
    ushortT* __restrict__ Wt_in, ushortT* __restrict__ Wt_x,
    ushortT* __restrict__ Wt_out, ushortT* __restrict__ x_bf) {
  __shared__ float tb[32][33];
  int bid = blockIdx.x;
  int tx = threadIdx.x, ty = threadIdx.y;  // (32,8)
  const float* in; ushortT* out; int K, N, bx, by;
  if (bid < 1024)      { in = W_in;  out = Wt_in;  K = 512;  N = 2048; bx = bid & 63; by = bid >> 6; }
  else if (bid < 1408) { int t2 = bid - 1024; in = W_x;   out = Wt_x;   K = 1024; N = 288;  bx = t2 % 12; by = t2 / 12; }
  else if (bid < 1920) { int t2 = bid - 1408; in = W_out; out = Wt_out; K = 1024; N = 512;  bx = t2 % 16; by = t2 / 16; }
  else {
    int i = (bid - 1920) * 256 + ty * 32 + tx;
    float4 v = ((const float4*)x)[i];
    ushort4 o; o.x = f2b(v.x); o.y = f2b(v.y); o.z = f2b(v.z); o.w = f2b(v.w);
    ((ushort4*)x_bf)[i] = o;
    return;
  }
  int n0 = bx * 32, k0 = by * 32;
  int flat = ty * 32 + tx;
  if (n0 < N) {
#pragma unroll
    for (int i = 0; i < 4; ++i)
      tb[ty + 8 * i][tx] = in[(size_t)(k0 + ty + 8 * i) * N + n0 + tx];
    __syncthreads();
#pragma unroll
    for (int j = 0; j < 2; ++j) {
      int idx = j * 256 + flat;        // 0..511
      int r = idx >> 4, c2 = idx & 15;
      ushort2 o;
      o.x = f2b(tb[2 * c2][r]);
      o.y = f2b(tb[2 * c2 + 1][r]);
      *(ushort2*)&out[(size_t)(n0 + r) * K + k0 + 2 * c2] = o;
    }
  } else {
    ushort2 z; z.x = 0; z.y = 0;
#pragma unroll
    for (int j = 0; j < 2; ++j) {
      int idx = j * 256 + flat;
      int r = idx >> 4, c2 = idx & 15;
      *(ushort2*)&out[(size_t)(n0 + r) * K + k0 + 2 * c2] = z;
    }
  }
}

// ---- depthwise causal conv, 4 d per thread (ushort4) ------------------------
__global__ __launch_bounds__(256) void conv_kernel(
    const ushortT* __restrict__ xr, const float* __restrict__ w,
    const float* __restrict__ b, ushortT* __restrict__ u) {
  int idx = blockIdx.x * blockDim.x + threadIdx.x;
  int g = idx & 255;
  int s = (idx >> 8) & (S_LEN - 1);
  int bb = idx >> 18;
  int d = g * 4;
  float4 bias = *(const float4*)&b[d];
  float4 w0 = *(const float4*)&w[(d + 0) * 4];
  float4 w1 = *(const float4*)&w[(d + 1) * 4];
  float4 w2 = *(const float4*)&w[(d + 2) * 4];
  float4 w3 = *(const float4*)&w[(d + 3) * 4];
  float a0 = bias.x, a1 = bias.y, a2 = bias.z, a3 = bias.w;
  const ushortT* xs = xr + (size_t)(bb * S_LEN) * (2 * DI) + d;
#pragma unroll
  for (int k = 0; k < 4; ++k) {
    int si = s - 3 + k;
    if (si >= 0) {
      ushort4 v = *(const ushort4*)&xs[(size_t)si * (2 * DI)];
      float wk0 = ((const float*)&w0)[k], wk1 = ((const float*)&w1)[k];
      float wk2 = ((const float*)&w2)[k], wk3 = ((const float*)&w3)[k];
      a0 = fmaf(b2f(v.x), wk0, a0);
      a1 = fmaf(b2f(v.y), wk1, a1);
      a2 = fmaf(b2f(v.z), wk2, a2);
      a3 = fmaf(b2f(v.w), wk3, a3);
    }
  }
  ushort4 o; o.x = f2b(a0); o.y = f2b(a1); o.z = f2b(a2); o.w = f2b(a3);
  *(ushort4*)&u[(size_t)idx * 4] = o;
}

// ---- megachunk: per (dg, bc) 64-d slice: dt-proj + softplus/clip + cumprod
//      + ut + Z = ut @ B^T. D stored bf16; zb layout [b][c][d][n]. ----------
__global__ __launch_bounds__(256) void megachunk(
    const float* __restrict__ dbl, const float* __restrict__ W_dt,
    const float* __restrict__ b_dt, const ushortT* __restrict__ u_bf,
    ushortT* __restrict__ D, ushortT* __restrict__ ut,
    ushortT* __restrict__ zb) {
  __shared__ ushortT Btl[128][72];   // B^T[n][s]
  __shared__ float   Dl[64][66];     // om -> cumprod D, [d][s]
  __shared__ ushortT utl[64][72];    // ut[d][s]
  __shared__ float   dtl[64][36];    // dbl[:,0:32]
  __shared__ ushortT Wl[32][68];     // W_dt slice bf16 [k][d]
  const int t = threadIdx.x;
  const int dg = blockIdx.x, bc = blockIdx.y;
  const int b = bc >> 4, c = bc & 15;
  const size_t rowbase = (size_t)(b * S_LEN + c * CL) * DI + dg * 64;

#pragma unroll
  for (int j = 0; j < 8; ++j) {
    int idx4 = j * 256 + t;
    int s = idx4 >> 5, n4 = (idx4 & 31) * 4;
    float4 v = *(const float4*)&dbl[(size_t)(bc * 64 + s) * 288 + 32 + n4];
    Btl[n4][s] = f2b(v.x); Btl[n4 + 1][s] = f2b(v.y);
    Btl[n4 + 2][s] = f2b(v.z); Btl[n4 + 3][s] = f2b(v.w);
  }
#pragma unroll
  for (int j = 0; j < 2; ++j) {
    int idx4 = j * 256 + t;
    int s = idx4 >> 3, k4 = (idx4 & 7) * 4;
    *(float4*)&dtl[s][k4] = *(const float4*)&dbl[(size_t)(bc * 64 + s) * 288 + k4];
  }
#pragma unroll
  for (int j = 0; j < 4; ++j) {
    int idx2 = j * 256 + t;
    int k = idx2 >> 5, d2 = (idx2 & 31) * 2;
    float2 v = *(const float2*)&W_dt[(size_t)k * DI + dg * 64 + d2];
    Wl[k][d2] = f2b(v.x); Wl[k][d2 + 1] = f2b(v.y);
  }
  __syncthreads();

  {
    int d = t & 63, sq = t >> 6;
    float wreg[32];
#pragma unroll
    for (int k = 0; k < 32; ++k) wreg[k] = b2f(Wl[k][d]);
    float bias = b_dt[dg * 64 + d] + 1e-4f;
#pragma unroll 4
    for (int j = 0; j < 16; ++j) {
      int s = sq * 16 + j;
      float acc = bias;
#pragma unroll
      for (int k = 0; k < 32; ++k) acc = fmaf(dtl[s][k], wreg[k], acc);
      acc = (acc > 20.f) ? acc : log1pf(expf(acc));
      acc = fminf(fmaxf(acc, 0.001f), 0.1f);
      Dl[d][s] = 1.f - acc;
    }
  }
  __syncthreads();

  if (t < 64) {
    float cum = 1.f;
#pragma unroll 16
    for (int s = 0; s < CL; ++s) { cum *= Dl[t][s]; Dl[t][s] = cum; }
  }
  __syncthreads();

  // ut build
#pragma unroll
  for (int j = 0; j < 2; ++j) {
    int idx8 = j * 256 + t;
    int s = idx8 >> 3, d8 = (idx8 & 7) * 8;
    float4 raw = *(const float4*)&u_bf[rowbase + (size_t)s * DI + d8];
    const ushortT* up = (const ushortT*)&raw;
#pragma unroll
    for (int k = 0; k < 8; ++k)
      utl[d8 + k][s] = f2b(b2f(up[k]) / Dl[d8 + k][s]);
  }
  __syncthreads();

  // Z = utl @ Btl^T (MFMA), global writes after; zb layout [b][c][d][n]
  {
    const int l = t & 63, w = t >> 6;
    f32x4 acc[8] = {};
#pragma unroll
    for (int kk = 0; kk < 2; ++kk) {
      short8 a = *(const short8*)&utl[w * 16 + (l & 15)][kk * 32 + (l >> 4) * 8];
#pragma unroll
      for (int n = 0; n < 8; ++n) {
        short8 bb = *(const short8*)&Btl[n * 16 + (l & 15)][kk * 32 + (l >> 4) * 8];
        acc[n] = __builtin_amdgcn_mfma_f32_16x16x32_bf16(a, bb, acc[n], 0, 0, 0);
      }
    }
#pragma unroll
    for (int n = 0; n < 8; ++n) {
      int gn = n * 16 + (l & 15);
#pragma unroll
      for (int i = 0; i < 4; ++i) {
        int d = dg * 64 + w * 16 + (l >> 4) * 4 + i;
        zb[(((size_t)(b * NC + c)) * DI + d) * 128 + gn] = f2b(acc[n][i]);
      }
    }
  }

  // D global write bf16 [s][d] (ushort8 = float4)
#pragma unroll
  for (int j = 0; j < 2; ++j) {
    int idx8 = j * 256 + t;
    int s = idx8 >> 3, d8 = (idx8 & 7) * 8;
    float4 v; ushortT* vp = (ushortT*)&v;
#pragma unroll
    for (int k = 0; k < 8; ++k) vp[k] = f2b(Dl[d8 + k][s]);
    *(float4*)&D[rowbase + (size_t)s * DI + d8] = v;
  }
  // ut global write (rows d)
#pragma unroll
  for (int j = 0; j < 2; ++j) {
    int idx8 = j * 256 + t;
    int d = idx8 >> 3, s8 = (idx8 & 7) * 8;
    float4 v; ushortT* vp = (ushortT*)&v;
#pragma unroll
    for (int k = 0; k < 8; ++k) vp[k] = utl[d][s8 + k];
    *(float4*)&ut[((size_t)bc * DI + dg * 64 + d) * CL + s8] = v;
  }
}

// ---- pass2: h_entry chain over chunks (layout [b][c][d][n], D bf16) --------
__global__ __launch_bounds__(256) void scan_pass2(
    const ushortT* __restrict__ zb, const ushortT* __restrict__ D,
    ushortT* __restrict__ hstb) {
  int wid = (blockIdx.x * blockDim.x + threadIdx.x) >> 6;  // 0..2047 = b*DI+d
  int lane = threadIdx.x & 63;
  int b = wid >> 10, d = wid & (DI - 1);
  float h0 = 0.f, h1 = 0.f;
#pragma unroll
  for (int c = 0; c < NC; ++c) {
    float dend = b2f(D[((size_t)(b * S_LEN + c * CL + CL - 1)) * DI + d]);
    size_t addr = (((size_t)(b * NC + c)) * DI + d) * 128 + 2 * lane;
    ushort2 z2 = *(const ushort2*)&zb[addr];
    ushort2 he;
    he.x = f2b(h0); he.y = f2b(h1);
    *(ushort2*)&hstb[addr] = he;
    h0 = dend * (h0 + b2f(z2.x));
    h1 = dend * (h1 + b2f(z2.y));
  }
}

// ---- Y (64-d blocks): stage B,C + ut + hstb + D tiles in LDS (coalesced);
//      G = tril(C.B^T); yr[t,d] = bf16( D*( G@ut + C@hstb ) + res ) ---------
__global__ __launch_bounds__(256) void gemm_y(
    const float* __restrict__ dbl, const ushortT* __restrict__ ut,
    const ushortT* __restrict__ hstb, const ushortT* __restrict__ D,
    const ushortT* __restrict__ xr_bf, ushortT* __restrict__ yr) {
  __shared__ ushortT Bl[64][136];
  __shared__ ushortT Cl[64][136];
  __shared__ ushortT Gl[64][72];
  __shared__ ushortT Ul[64][72];    // ut tile [d][s]
  __shared__ ushortT Hl[64][136];   // hstb tile [d][n]
  __shared__ ushortT Dl2[64][72];   // D tile [t][d] bf16
  const int tid = threadIdx.x;
  const int l = tid & 63, w = tid >> 6;
  const int bc = blockIdx.y, d0 = blockIdx.x * 64;
  const int b = bc >> 4, c = bc & 15;
  const int brow = b * S_LEN + c * CL;
  // stage Ul: ut tile contiguous 8KB
#pragma unroll
  for (int j = 0; j < 2; ++j) {
    int idx4 = j * 256 + tid;
    int dr = idx4 >> 3, s8 = (idx4 & 7) * 8;
    float4 v = *(const float4*)&ut[((size_t)bc * DI + d0 + dr) * CL + s8];
    *(float4*)&Ul[dr][s8] = v;
  }
  // stage Hl: hstb tile contiguous 16KB
#pragma unroll
  for (int j = 0; j < 4; ++j) {
    int idx4 = j * 256 + tid;
    int dr = idx4 >> 4, n8 = (idx4 & 15) * 8;
    float4 v = *(const float4*)&hstb[(((size_t)(b * NC + c)) * DI + d0 + dr) * 128 + n8];
    *(float4*)&Hl[dr][n8] = v;
  }
  // stage Dl2: D tile [64 t][64 d] (rows 128B)
#pragma unroll
  for (int j = 0; j < 2; ++j) {
    int idx4 = j * 256 + tid;
    int tr = idx4 >> 3, d8 = (idx4 & 7) * 8;
    float4 v = *(const float4*)&D[((size_t)(brow + tr)) * DI + d0 + d8];
    *(float4*)&Dl2[tr][d8] = v;
  }
  // stage B|C rows (float4)
#pragma unroll
  for (int j = 0; j < 16; ++j) {
    int idx4 = j * 256 + tid;
    int row = idx4 >> 6, c4 = (idx4 & 63) * 4;
    float4 v = *(const float4*)&dbl[(size_t)(bc * 64 + row) * 288 + 32 + c4];
    ushortT o0 = f2b(v.x), o1 = f2b(v.y), o2 = f2b(v.z), o3 = f2b(v.w);
    if (c4 < 128) { Bl[row][c4] = o0; Bl[row][c4+1] = o1; Bl[row][c4+2] = o2; Bl[row][c4+3] = o3; }
    else { int cc = c4 - 128; Cl[row][cc] = o0; Cl[row][cc+1] = o1; Cl[row][cc+2] = o2; Cl[row][cc+3] = o3; }
  }
  __syncthreads();
  // G = tril(C @ B^T) -> Gl
  {
    f32x4 gacc[4] = {};
#pragma unroll
    for (int kk = 0; kk < 4; ++kk) {
      short8 a = *(const short8*)&Cl[w * 16 + (l & 15)][kk * 32 + (l >> 4) * 8];
#pragma unroll
      for (int nf = 0; nf < 4; ++nf) {
        short8 bb = *(const short8*)&Bl[nf * 16 + (l & 15)][kk * 32 + (l >> 4) * 8];
        gacc[nf] = __builtin_amdgcn_mfma_f32_16x16x32_bf16(a, bb, gacc[nf], 0, 0, 0);
      }
    }
#pragma unroll
    for (int nf = 0; nf < 4; ++nf) {
      int s = nf * 16 + (l & 15);
#pragma unroll
      for (int i = 0; i < 4; ++i) {
        int tr = w * 16 + (l >> 4) * 4 + i;
        Gl[tr][s] = f2b((s <= tr) ? gacc[nf][i] : 0.f);
      }
    }
  }
  __syncthreads();
  f32x4 acc[4] = {};
  // phase 1: K=64 (s): A = Gl rows, B = Ul rows
#pragma unroll
  for (int kk = 0; kk < 2; ++kk) {
    short8 a = *(const short8*)&Gl[w * 16 + (l & 15)][kk * 32 + (l >> 4) * 8];
#pragma unroll
    for (int n = 0; n < 4; ++n) {
      short8 bb = *(const short8*)&Ul[n * 16 + (l & 15)][kk * 32 + (l >> 4) * 8];
      acc[n] = __builtin_amdgcn_mfma_f32_16x16x32_bf16(a, bb, acc[n], 0, 0, 0);
    }
  }
  // phase 2: K=128 (n-state): A = Cl rows, B = Hl rows
#pragma unroll
  for (int kk = 0; kk < 4; ++kk) {
    short8 a = *(const short8*)&Cl[w * 16 + (l & 15)][kk * 32 + (l >> 4) * 8];
#pragma unroll
    for (int n = 0; n < 4; ++n) {
      short8 bb = *(const short8*)&Hl[n * 16 + (l & 15)][kk * 32 + (l >> 4) * 8];
      acc[n] = __builtin_amdgcn_mfma_f32_16x16x32_bf16(a, bb, acc[n], 0, 0, 0);
    }
  }
#pragma unroll
  for (int n = 0; n < 4; ++n) {
    int dl = n * 16 + (l & 15);
    int d = d0 + dl;
#pragma unroll
    for (int i = 0; i < 4; ++i) {
      int tl = w * 16 + (l >> 4) * 4 + i;
      int gr = brow + tl;
      float Dv = b2f(Dl2[tl][dl]);
      float res = b2f(xr_bf[(size_t)gr * 2048 + 1024 + d]);
      yr[(size_t)gr * DI + d] = f2b(acc[n][i] * Dv + res);
    }
  }
}

extern "C" void kernel_launch(void* const* d_in, const int* in_sizes, int n_in,
                              void* d_out, int out_size, void* d_ws, size_t ws_size,
                              hipStream_t stream) {
  const float* x      = (const float*)d_in[0];
  const float* W_in   = (const float*)d_in[1];
  const float* conv_w = (const float*)d_in[2];
  const float* conv_b = (const float*)d_in[3];
  const float* W_x    = (const float*)d_in[4];
  const float* W_dt   = (const float*)d_in[5];
  const float* b_dt   = (const float*)d_in[6];
  const float* W_out  = (const float*)d_in[7];
  float* out = (float*)d_out;
  float* ws = (float*)d_ws;

  // workspace (float units), all disjoint (Dc now bf16, uses half its slot)
  ushortT* xr_bf = (ushortT*)ws;                  // [2048,2048] bf16
  ushortT* u_bf  = (ushortT*)(ws + 2097152);      // [2048,1024] bf16
  float*   dbl   = ws + 3145728;                  // [2048,288] fp32
  ushortT* Dc    = (ushortT*)(ws + 3735552);      // [2048,1024] bf16
  ushortT* ut    = (ushortT*)(ws + 5832704);      // [32,1024,64] bf16
  ushortT* zb    = (ushortT*)(ws + 6881280);      // [2,16,1024,128] bf16
  ushortT* hstb  = (ushortT*)(ws + 8978432);      // [2,16,1024,128] bf16
  ushortT* x_bf  = (ushortT*)(ws + 11075584);     // [2048,512] bf16
  ushortT* Wt_in = (ushortT*)(ws + 11599872);     // [2048,512] bf16
  ushortT* Wt_x  = (ushortT*)(ws + 12124160);     // [384,1024] bf16
  ushortT* Wt_out= (ushortT*)(ws + 12320768);     // [512,1024] bf16
  ushortT* yr_bf = (ushortT*)(ws + 12582912);     // [2048,1024] bf16

  dim3 blk(256);
  // 1) weight transposes + x cvt
  prep_all<<<2944, dim3(32, 8), 0, stream>>>(W_in, W_x, W_out, x,
                                             Wt_in, Wt_x, Wt_out, x_bf);
  // 2) in-proj: xr = x @ W_in (bf16)  M=2048 N=2048 K=512; 64-tile 32x32=1024
  gemm64<1><<<1024, blk, 0, stream>>>(x_bf, Wt_in, xr_bf, 2 * DI, DM, 2 * DI, 32);
  // 3) conv -> u (bf16)
  conv_kernel<<<2048, blk, 0, stream>>>(xr_bf, conv_w, conv_b, u_bf);
  // 4) x-proj: dbl = u @ W_x (fp32)  M=2048 N=288 K=1024; 64-tile 5x32=160
  gemm64<0><<<160, blk, 0, stream>>>(u_bf, Wt_x, dbl, DTR + 2 * DS, DI, DTR + 2 * DS, 5);
  // 5) megachunk: dt-proj + decay + ut + Z  (512 blocks, 2/CU)
  megachunk<<<dim3(16, 32), blk, 0, stream>>>(dbl, W_dt, b_dt, u_bf, Dc, ut, zb);
  // 6) chunk-boundary combine -> hstb (entry states, bf16)
  scan_pass2<<<512, blk, 0, stream>>>(zb, Dc, hstb);
  // 7) Y = D*(G@ut + C@h_entry) + res -> yr_bf  (512 blocks)
  gemm_y<<<dim3(16, 32), blk, 0, stream>>>(dbl, ut, hstb, Dc, xr_bf, yr_bf);
  // 8) out-proj: out = yr @ W_out (fp32)  M=2048 N=512 K=1024; 64-tile 8x32=256
  gemm64<0><<<256, blk, 0, stream>>>(yr_bf, Wt_out, out, DM, DI, DM, 8);
}